// Round 7
// baseline (587.213 us; speedup 1.0000x reference)
//
#include <hip/hip_runtime.h>
#include <math.h>

// Round 10b: 8-phase 256-tile GEMM template (m201 structure). Resubmit of
// round 10 with the mid-line "#pragma unroll" compile errors fixed (a
// preprocessor directive can't follow '{' on the same line).
// gemm8<EPI,BM,BN>: 512 thr, 8 waves (2Mx4N), BK=64, 2 LDS dbufs.
//   256x256 for qkv/fc; 128x256 for proj/fc2 (N=1024 -> 256 blocks = 1/CU).
// Per K-tile, 4 phases: {stage-issues | ds_read quadrant | lgkmcnt(0) |
// setprio(1) MFMA cluster setprio(0) | barrier}. B-frags register-held across
// paired phases. Tile entry: vmcnt(0) (outstanding == tile t's own loads,
// issued 1-4 phases earlier) + barrier. Swizzle: phys granule = logical ^
// (row&7) on 128B rows via pre-swizzled global source + same involution on
// reads (round 9's measured-zero-conflict pattern at BK=64).
// Flash (paired q-tiles) / LN / wconv unchanged.
//
// ws: [0,16M) lnbuf | [16,48M) qk | [48,64M) vT | [64,80M) ybuf
//     [80,144M) h | [144,170M) wT

#define M_ROWS 8192
#define T_SEQ 2048
#define N_EMB 1024
#define N_HEADS 16
#define HEAD_D 64

typedef _Float16 f16;
typedef __attribute__((ext_vector_type(8))) _Float16 f16x8;
typedef __attribute__((ext_vector_type(4))) _Float16 f16x4;
typedef __attribute__((ext_vector_type(4))) float f32x4;

__device__ __forceinline__ void async16(void* lds, const void* g) {
    __builtin_amdgcn_global_load_lds(
        (const __attribute__((address_space(1))) unsigned int*)g,
        (__attribute__((address_space(3))) unsigned int*)lds, 16, 0, 0);
}

__device__ __forceinline__ float gelu_tanh(float v) {
    float u = 0.7978845608028654f * (v + 0.044715f * v * v * v);
    float e = __expf(2.0f * u);
    float t = 1.0f - 2.0f / (e + 1.0f);
    return 0.5f * v * (1.0f + t);
}

// ---------------------------------------------------------------- weight convert
__launch_bounds__(256)
__global__ void wconv_kernel(const float* __restrict__ W, f16* __restrict__ WT,
                             int K, int N) {
    __shared__ float t[32][33];
    int tx = threadIdx.x & 31, ty = threadIdx.x >> 5;
    int n0 = blockIdx.x * 32, k0 = blockIdx.y * 32;
    #pragma unroll
    for (int r = 0; r < 4; r++)
        t[ty * 4 + r][tx] = W[(size_t)(k0 + ty * 4 + r) * N + n0 + tx];
    __syncthreads();
    #pragma unroll
    for (int r = 0; r < 4; r++)
        WT[(size_t)(n0 + ty * 4 + r) * K + k0 + tx] = (f16)t[tx][ty * 4 + r];
}

// ---------------------------------------------------------------- LayerNorm -> f16
__launch_bounds__(256)
__global__ void ln_kernel(const float* __restrict__ x, const float* __restrict__ g,
                          const float* __restrict__ b, f16* __restrict__ y) {
    int row = blockIdx.x;
    int tid = threadIdx.x;
    const float* xr = x + (size_t)row * N_EMB;
    float4 v = *(const float4*)(xr + tid * 4);
    float s  = v.x + v.y + v.z + v.w;
    float sq = v.x * v.x + v.y * v.y + v.z * v.z + v.w * v.w;
    #pragma unroll
    for (int off = 32; off > 0; off >>= 1) {
        s  += __shfl_down(s, off);
        sq += __shfl_down(sq, off);
    }
    __shared__ float ws_[4], wq_[4];
    __shared__ float mean_s, rstd_s;
    int lane = tid & 63, wid = tid >> 6;
    if (lane == 0) { ws_[wid] = s; wq_[wid] = sq; }
    __syncthreads();
    if (tid == 0) {
        float st = ws_[0] + ws_[1] + ws_[2] + ws_[3];
        float qt = wq_[0] + wq_[1] + wq_[2] + wq_[3];
        float mu = st * (1.0f / N_EMB);
        float var = qt * (1.0f / N_EMB) - mu * mu;
        mean_s = mu;
        rstd_s = rsqrtf(var + 1e-5f);
    }
    __syncthreads();
    float mu = mean_s, r = rstd_s;
    float4 gv = *(const float4*)(g + tid * 4);
    float4 bv = *(const float4*)(b + tid * 4);
    f16x4 o;
    o.x = (f16)((v.x - mu) * r * gv.x + bv.x);
    o.y = (f16)((v.y - mu) * r * gv.y + bv.y);
    o.z = (f16)((v.z - mu) * r * gv.z + bv.z);
    o.w = (f16)((v.w - mu) * r * gv.w + bv.w);
    *(f16x4*)(y + (size_t)row * N_EMB + tid * 4) = o;
}

// ---------------------------------------------------------------- GEMM 8-phase
// EPI: 0 f32 | 1 f32 + f32 residual | 2 gelu->f16 | 3 qkv split
template <int EPI, int BM, int BN>
__launch_bounds__(512, 2)
__global__ void gemm8(const f16* __restrict__ A, const f16* __restrict__ Bt,
                      const float* __restrict__ bias, const float* __restrict__ res,
                      float* __restrict__ Cf, f16* __restrict__ Ch,
                      f16* __restrict__ vT, int K, int N) {
    constexpr int MI = BM / 32;          // m frags per wave (8 / 4)
    constexpr int MH = MI / 2;           // frags per m-half
    constexpr int NJ = BN / 64;          // n frags per wave (4)
    constexpr int AROUNDS = BM / 64;     // staging rounds for A (4 / 2)
    constexpr int BROUNDS = BN / 64;     // staging rounds for B (4)
    constexpr int ROUNDS = AROUNDS + BROUNDS;
    constexpr int P1E = (ROUNDS == 8) ? 3 : 2;   // stage-round split per phase
    constexpr int P2E = (ROUNDS == 8) ? 6 : 4;
    __shared__ f16 As[2][BM * 64];
    __shared__ f16 Bs[2][BN * 64];

    int tid = threadIdx.x;
    int lane = tid & 63, wave = tid >> 6;
    int wr = wave >> 2, wc = wave & 3;           // 2 x 4 wave grid
    int quad = lane >> 4, l16 = lane & 15;

    // bijective XCD swizzle (all grids divisible by 8)
    int nx = gridDim.x, nwg = nx * gridDim.y;
    int orig = blockIdx.y * nx + blockIdx.x;
    int cpx = nwg >> 3;
    int swz = (orig & 7) * cpx + (orig >> 3);
    int m0 = (swz / nx) * BM, n0 = (swz % nx) * BN;

    // staging: round r = 512 thr x 16B = 8KB = 64 rows of 128B.
    // phys granule (tid&7) of row srow holds logical granule (tid&7)^(srow&7).
    int srow = tid >> 3;                 // 0..63
    int sglog = (tid & 7) ^ (srow & 7);
    const f16* pa[AROUNDS];
    const f16* pb[BROUNDS];
    #pragma unroll
    for (int r = 0; r < AROUNDS; r++)
        pa[r] = A + (size_t)(m0 + r * 64 + srow) * K + sglog * 8;
    #pragma unroll
    for (int r = 0; r < BROUNDS; r++)
        pb[r] = Bt + (size_t)(n0 + r * 64 + srow) * K + sglog * 8;

    int nt = K >> 6;

    // stage round r of tile t into buffer buf
    auto stage = [&](int t, int buf, int r) {
        if (r < AROUNDS)
            async16((char*)As[buf] + (size_t)(r * 512 + tid) * 16,
                    pa[r] + (size_t)t * 64);
        else
            async16((char*)Bs[buf] + (size_t)((r - AROUNDS) * 512 + tid) * 16,
                    pb[r - AROUNDS] + (size_t)t * 64);
    };

    // prologue: tile 0 -> buf 0
    #pragma unroll
    for (int r = 0; r < ROUNDS; r++) stage(0, 0, r);

    f32x4 acc[MI][NJ] = {};
    for (int t = 0; t < nt; t++) {
        int p = t & 1;
        asm volatile("s_waitcnt vmcnt(0)" ::: "memory");  // tile t landed
        __builtin_amdgcn_s_barrier();                     // visible to all waves
        const f16* as = As[p];
        const f16* bs = Bs[p];
        bool pf = (t + 1 < nt);
        f16x8 a0[MH], a1[MH], b0[NJ], b1[NJ];

        // ---- phase 1: (m-half 0, kstep 0)
        if (pf) {
            #pragma unroll
            for (int r = 0; r < P1E; r++) stage(t + 1, p ^ 1, r);
        }
        #pragma unroll
        for (int i = 0; i < MH; i++) {
            int row = wr * (BM / 2) + i * 16 + l16;
            a0[i] = *(const f16x8*)&as[row * 64 + ((quad) ^ (row & 7)) * 8];
        }
        #pragma unroll
        for (int j = 0; j < NJ; j++) {
            int row = wc * (BN / 4) + j * 16 + l16;
            b0[j] = *(const f16x8*)&bs[row * 64 + ((quad) ^ (row & 7)) * 8];
        }
        asm volatile("s_waitcnt lgkmcnt(0)" ::: "memory");
        __builtin_amdgcn_s_setprio(1);
        #pragma unroll
        for (int i = 0; i < MH; i++) {
            #pragma unroll
            for (int j = 0; j < NJ; j++)
                acc[i][j] = __builtin_amdgcn_mfma_f32_16x16x32_f16(
                    a0[i], b0[j], acc[i][j], 0, 0, 0);
        }
        __builtin_amdgcn_s_setprio(0);
        __builtin_amdgcn_s_barrier();

        // ---- phase 2: (m-half 1, kstep 0)  [b0 held]
        if (pf) {
            #pragma unroll
            for (int r = P1E; r < P2E; r++) stage(t + 1, p ^ 1, r);
        }
        #pragma unroll
        for (int i = 0; i < MH; i++) {
            int row = wr * (BM / 2) + (MH + i) * 16 + l16;
            a1[i] = *(const f16x8*)&as[row * 64 + ((quad) ^ (row & 7)) * 8];
        }
        asm volatile("s_waitcnt lgkmcnt(0)" ::: "memory");
        __builtin_amdgcn_s_setprio(1);
        #pragma unroll
        for (int i = 0; i < MH; i++) {
            #pragma unroll
            for (int j = 0; j < NJ; j++)
                acc[MH + i][j] = __builtin_amdgcn_mfma_f32_16x16x32_f16(
                    a1[i], b0[j], acc[MH + i][j], 0, 0, 0);
        }
        __builtin_amdgcn_s_setprio(0);
        __builtin_amdgcn_s_barrier();

        // ---- phase 3: (m-half 0, kstep 1)
        if (pf) {
            #pragma unroll
            for (int r = P2E; r < ROUNDS; r++) stage(t + 1, p ^ 1, r);
        }
        #pragma unroll
        for (int i = 0; i < MH; i++) {
            int row = wr * (BM / 2) + i * 16 + l16;
            a0[i] = *(const f16x8*)&as[row * 64 + ((4 + quad) ^ (row & 7)) * 8];
        }
        #pragma unroll
        for (int j = 0; j < NJ; j++) {
            int row = wc * (BN / 4) + j * 16 + l16;
            b1[j] = *(const f16x8*)&bs[row * 64 + ((4 + quad) ^ (row & 7)) * 8];
        }
        asm volatile("s_waitcnt lgkmcnt(0)" ::: "memory");
        __builtin_amdgcn_s_setprio(1);
        #pragma unroll
        for (int i = 0; i < MH; i++) {
            #pragma unroll
            for (int j = 0; j < NJ; j++)
                acc[i][j] = __builtin_amdgcn_mfma_f32_16x16x32_f16(
                    a0[i], b1[j], acc[i][j], 0, 0, 0);
        }
        __builtin_amdgcn_s_setprio(0);
        __builtin_amdgcn_s_barrier();

        // ---- phase 4: (m-half 1, kstep 1)  [b1 held]
        #pragma unroll
        for (int i = 0; i < MH; i++) {
            int row = wr * (BM / 2) + (MH + i) * 16 + l16;
            a1[i] = *(const f16x8*)&as[row * 64 + ((4 + quad) ^ (row & 7)) * 8];
        }
        asm volatile("s_waitcnt lgkmcnt(0)" ::: "memory");
        __builtin_amdgcn_s_setprio(1);
        #pragma unroll
        for (int i = 0; i < MH; i++) {
            #pragma unroll
            for (int j = 0; j < NJ; j++)
                acc[MH + i][j] = __builtin_amdgcn_mfma_f32_16x16x32_f16(
                    a1[i], b1[j], acc[MH + i][j], 0, 0, 0);
        }
        __builtin_amdgcn_s_setprio(0);
        __builtin_amdgcn_s_barrier();
    }

    // epilogue: C/D layout col=lane&15, row=quad*4+r
    #pragma unroll
    for (int i = 0; i < MI; i++) {
        int row0 = m0 + wr * (BM / 2) + i * 16 + quad * 4;
        #pragma unroll
        for (int j = 0; j < NJ; j++) {
            int col = n0 + wc * (BN / 4) + j * 16 + l16;
            float bb = bias[col];
            if (EPI == 3) {
                if (n0 < 2048) {
                    #pragma unroll
                    for (int r = 0; r < 4; r++)
                        Ch[(size_t)(row0 + r) * 2048 + col] = (f16)(acc[i][j][r] + bb);
                } else {
                    int hh = (col - 2048) >> 6, dd = col & 63;
                    int bb_ = row0 >> 11, t0 = row0 & 2047;
                    f16x4 pk;
                    pk.x = (f16)(acc[i][j][0] + bb);
                    pk.y = (f16)(acc[i][j][1] + bb);
                    pk.z = (f16)(acc[i][j][2] + bb);
                    pk.w = (f16)(acc[i][j][3] + bb);
                    *(f16x4*)(vT + ((size_t)(bb_ * 16 + hh) * 64 + dd) * 2048 + t0) = pk;
                }
            } else {
                #pragma unroll
                for (int r = 0; r < 4; r++) {
                    size_t idx = (size_t)(row0 + r) * N + col;
                    float v = acc[i][j][r] + bb;
                    if (EPI == 1) v += res[idx];
                    if (EPI == 2) Ch[idx] = (f16)gelu_tanh(v);
                    else          Cf[idx] = v;
                }
            }
        }
    }
}

// ---------------------------------------------------------------- MFMA flash
// 256 thr = 4 waves; 128 q-rows per tile (wave w owns 32), 128-wide j-tiles.
// Paired q-tiles (qt = 15-x then x): every block does 17 j-iterations.
__launch_bounds__(256, 2)
__global__ void flash_kernel(const f16* __restrict__ qk, const f16* __restrict__ vT,
                             f16* __restrict__ y) {
    __shared__ __align__(16) char smem[67584];
    f16* Ks = (f16*)smem;                      // [128 j][8 g of 8 d], g^=(j&7)
    f16* Vs = (f16*)(smem + 16384);            // [64 d][16 g of 8 j], g^=(d&7)
    int tid = threadIdx.x;
    int lane = tid & 63, w = tid >> 6;
    int quad = lane >> 4, l16 = lane & 15;
    f16* Ps = (f16*)(smem + 32768 + w * 8704); // per-wave [32 q][136 j]

    int bh = blockIdx.y;
    int b = bh >> 4, h = bh & 15;

    for (int half = 0; half < 2; half++) {
        int qt = half ? (int)blockIdx.x : 15 - (int)blockIdx.x;
        int q0 = qt * 128;

        f16x8 qf[2][2];
        #pragma unroll
        for (int qn = 0; qn < 2; qn++) {
            int q = q0 + w * 32 + qn * 16 + l16;
            #pragma unroll
            for (int dblk = 0; dblk < 2; dblk++) {
                f16x8 t = *(const f16x8*)(qk + (size_t)(b * T_SEQ + q) * 2048 +
                                          h * 64 + dblk * 32 + quad * 8);
                #pragma unroll
                for (int e = 0; e < 8; e++) t[e] = t[e] * (f16)0.125f;
                qf[qn][dblk] = t;
            }
        }

        float m_r[2] = {-INFINITY, -INFINITY};
        float l_r[2] = {0.0f, 0.0f};
        f32x4 Oacc[2][4] = {};

        for (int jt = 0; jt <= qt; jt++) {
            int j0 = jt * 128;
            __syncthreads();
            #pragma unroll
            for (int i = 0; i < 4; i++) {
                int L = i * 256 + tid;
                int j = L >> 3, g1 = L & 7;
                int g = g1 ^ (j & 7);
                async16((char*)Ks + (size_t)L * 16,
                        qk + (size_t)(b * T_SEQ + j0 + j) * 2048 + 1024 + h * 64 + g * 8);
            }
            #pragma unroll
            for (int i = 0; i < 4; i++) {
                int L = i * 256 + tid;
                int d = L >> 4, g1 = L & 15;
                int g = (g1 & 8) | ((g1 ^ d) & 7);
                async16((char*)Vs + (size_t)L * 16,
                        vT + ((size_t)(bh) * 64 + d) * 2048 + j0 + g * 8);
            }
            __syncthreads();

            f32x4 S[8][2];
            #pragma unroll
            for (int jm = 0; jm < 8; jm++) {
                f16x8 kf[2];
                #pragma unroll
                for (int dblk = 0; dblk < 2; dblk++) {
                    int j = jm * 16 + l16;
                    int g = (dblk * 4 + quad) ^ (j & 7);
                    kf[dblk] = *(const f16x8*)(Ks + (size_t)(j * 8 + g) * 8);
                }
                #pragma unroll
                for (int qn = 0; qn < 2; qn++) {
                    f32x4 s = {};
                    s = __builtin_amdgcn_mfma_f32_16x16x32_f16(kf[0], qf[qn][0], s, 0, 0, 0);
                    s = __builtin_amdgcn_mfma_f32_16x16x32_f16(kf[1], qf[qn][1], s, 0, 0, 0);
                    S[jm][qn] = s;
                }
            }

            if (jt == qt) {
                #pragma unroll
                for (int jm = 0; jm < 8; jm++)
                    #pragma unroll
                    for (int qn = 0; qn < 2; qn++)
                        #pragma unroll
                        for (int r = 0; r < 4; r++) {
                            int jl = jm * 16 + quad * 4 + r;
                            int ql = w * 32 + qn * 16 + l16;
                            if (jl > ql) S[jm][qn][r] = -1e30f;
                        }
            }

            float alpha[2];
            #pragma unroll
            for (int qn = 0; qn < 2; qn++) {
                float tmax = -INFINITY;
                #pragma unroll
                for (int jm = 0; jm < 8; jm++)
                    #pragma unroll
                    for (int r = 0; r < 4; r++)
                        tmax = fmaxf(tmax, S[jm][qn][r]);
                tmax = fmaxf(tmax, __shfl_xor(tmax, 16));
                tmax = fmaxf(tmax, __shfl_xor(tmax, 32));
                float mnew = fmaxf(m_r[qn], tmax);
                alpha[qn] = __expf(m_r[qn] - mnew);
                m_r[qn] = mnew;
                float rsum = 0.0f;
                #pragma unroll
                for (int jm = 0; jm < 8; jm++)
                    #pragma unroll
                    for (int r = 0; r < 4; r++) {
                        float p = __expf(S[jm][qn][r] - mnew);
                        S[jm][qn][r] = p;
                        rsum += p;
                    }
                rsum += __shfl_xor(rsum, 16);
                rsum += __shfl_xor(rsum, 32);
                l_r[qn] = l_r[qn] * alpha[qn] + rsum;
            }

            #pragma unroll
            for (int jm = 0; jm < 8; jm++)
                #pragma unroll
                for (int qn = 0; qn < 2; qn++) {
                    f16x4 pk;
                    pk.x = (f16)S[jm][qn][0];
                    pk.y = (f16)S[jm][qn][1];
                    pk.z = (f16)S[jm][qn][2];
                    pk.w = (f16)S[jm][qn][3];
                    *(f16x4*)(Ps + (size_t)(qn * 16 + l16) * 136 + jm * 16 + quad * 4) = pk;
                }

            float aPV[2][4];
            #pragma unroll
            for (int m = 0; m < 2; m++)
                #pragma unroll
                for (int r = 0; r < 4; r++)
                    aPV[m][r] = __shfl(alpha[m], quad * 20 + r);
            #pragma unroll
            for (int m = 0; m < 2; m++)
                #pragma unroll
                for (int n = 0; n < 4; n++)
                    #pragma unroll
                    for (int r = 0; r < 4; r++)
                        Oacc[m][n][r] *= aPV[m][r];

            #pragma unroll
            for (int kblk = 0; kblk < 4; kblk++) {
                f16x8 pf[2];
                #pragma unroll
                for (int m = 0; m < 2; m++)
                    pf[m] = *(const f16x8*)(Ps + (size_t)(m * 16 + l16) * 136 +
                                            kblk * 32 + quad * 8);
                f16x8 vf[4];
                #pragma unroll
                for (int n = 0; n < 4; n++) {
                    int d = n * 16 + l16;
                    int g = (kblk * 4 + quad);
                    int gs = (g & 8) | ((g ^ d) & 7);
                    vf[n] = *(const f16x8*)(Vs + (size_t)(d * 16 + gs) * 8);
                }
                #pragma unroll
                for (int m = 0; m < 2; m++)
                    #pragma unroll
                    for (int n = 0; n < 4; n++)
                        Oacc[m][n] = __builtin_amdgcn_mfma_f32_16x16x32_f16(
                            pf[m], vf[n], Oacc[m][n], 0, 0, 0);
            }
        }

        #pragma unroll
        for (int m = 0; m < 2; m++) {
            float lPV[4];
            #pragma unroll
            for (int r = 0; r < 4; r++)
                lPV[r] = 1.0f / __shfl(l_r[m], quad * 20 + r);
            #pragma unroll
            for (int n = 0; n < 4; n++) {
                #pragma unroll
                for (int r = 0; r < 4; r++) {
                    int q = q0 + w * 32 + m * 16 + quad * 4 + r;
                    y[(size_t)(b * T_SEQ + q) * N_EMB + h * 64 + n * 16 + l16] =
                        (f16)(Oacc[m][n][r] * lPV[r]);
                }
            }
        }
    }
}

// ---------------------------------------------------------------- launch
extern "C" void kernel_launch(void* const* d_in, const int* in_sizes, int n_in,
                              void* d_out, int out_size, void* d_ws, size_t ws_size,
                              hipStream_t stream) {
    const float* x      = (const float*)d_in[0];
    const float* ln1_g  = (const float*)d_in[1];
    const float* ln1_b  = (const float*)d_in[2];
    const float* w_attn = (const float*)d_in[3];
    const float* b_attn = (const float*)d_in[4];
    const float* w_proj = (const float*)d_in[5];
    const float* b_proj = (const float*)d_in[6];
    const float* ln2_g  = (const float*)d_in[7];
    const float* ln2_b  = (const float*)d_in[8];
    const float* w_fc   = (const float*)d_in[9];
    const float* b_fc   = (const float*)d_in[10];
    const float* w_fc2  = (const float*)d_in[11];
    const float* b_fc2  = (const float*)d_in[12];
    float* out = (float*)d_out;

    const size_t MB = 1024 * 1024;
    char* ws = (char*)d_ws;
    f16*   lnbuf = (f16*)ws;                        // 16 MB
    f16*   qkbuf = (f16*)(ws + 16 * MB);            // 32 MB: [M][2048] Q|K
    f16*   vTbuf = (f16*)(ws + 48 * MB);            // 16 MB: [b][h][d][t]
    f16*   ybuf  = (f16*)(ws + 64 * MB);            // 16 MB
    f16*   h     = (f16*)(ws + 80 * MB);            // 64 MB
    f16*   wT    = (f16*)(ws + 144 * MB);           // 26 MB
    f16* wT_attn = wT;
    f16* wT_proj = wT_attn + (size_t)3072 * 1024;
    f16* wT_fc   = wT_proj + (size_t)1024 * 1024;
    f16* wT_fc2  = wT_fc   + (size_t)1024 * 4096;

    wconv_kernel<<<dim3(3072 / 32, 1024 / 32), 256, 0, stream>>>(w_attn, wT_attn, 1024, 3072);
    wconv_kernel<<<dim3(1024 / 32, 1024 / 32), 256, 0, stream>>>(w_proj, wT_proj, 1024, 1024);
    wconv_kernel<<<dim3(4096 / 32, 1024 / 32), 256, 0, stream>>>(w_fc,   wT_fc,   1024, 4096);
    wconv_kernel<<<dim3(1024 / 32, 4096 / 32), 256, 0, stream>>>(w_fc2,  wT_fc2,  4096, 1024);

    ln_kernel<<<M_ROWS, 256, 0, stream>>>(x, ln1_g, ln1_b, lnbuf);
    gemm8<3, 256, 256><<<dim3(3072 / 256, M_ROWS / 256), 512, 0, stream>>>(
        lnbuf, wT_attn, b_attn, nullptr, nullptr, qkbuf, vTbuf, 1024, 3072);
    flash_kernel<<<dim3(8, 64), 256, 0, stream>>>(qkbuf, vTbuf, ybuf);
    gemm8<1, 128, 256><<<dim3(1024 / 256, M_ROWS / 128), 512, 0, stream>>>(
        ybuf, wT_proj, b_proj, x, out, nullptr, nullptr, 1024, 1024);
    ln_kernel<<<M_ROWS, 256, 0, stream>>>(out, ln2_g, ln2_b, lnbuf);
    gemm8<2, 256, 256><<<dim3(4096 / 256, M_ROWS / 256), 512, 0, stream>>>(
        lnbuf, wT_fc, b_fc, nullptr, nullptr, h, nullptr, 1024, 4096);
    gemm8<1, 128, 256><<<dim3(1024 / 256, M_ROWS / 128), 512, 0, stream>>>(
        h, wT_fc2, b_fc2, out, out, nullptr, nullptr, 4096, 1024);
}

// Round 8
// 546.363 us; speedup vs baseline: 1.0748x; 1.0748x over previous
//
#include <hip/hip_runtime.h>
#include <math.h>

// Round 11: counted-vmcnt fix for the 8-phase GEMM (T4 — m218's lever).
// Tile entry now: issue first P1E staging rounds of t+1 into buf p^1, THEN
// s_waitcnt vmcnt(P1E) (waits for tile t's 8 loads only; t+1's head stays in
// flight) + barrier. Per-phase schedule per m201: {ds_read issue; stage issue;
// barrier; lgkmcnt(0); setprio(1); MFMA; setprio(0); barrier}. Only the last
// tile drains vmcnt(0). Everything else identical to round 10b (correct).
//
// ws: [0,16M) lnbuf | [16,48M) qk | [48,64M) vT | [64,80M) ybuf
//     [80,144M) h | [144,170M) wT

#define M_ROWS 8192
#define T_SEQ 2048
#define N_EMB 1024
#define N_HEADS 16
#define HEAD_D 64

typedef _Float16 f16;
typedef __attribute__((ext_vector_type(8))) _Float16 f16x8;
typedef __attribute__((ext_vector_type(4))) _Float16 f16x4;
typedef __attribute__((ext_vector_type(4))) float f32x4;

__device__ __forceinline__ void async16(void* lds, const void* g) {
    __builtin_amdgcn_global_load_lds(
        (const __attribute__((address_space(1))) unsigned int*)g,
        (__attribute__((address_space(3))) unsigned int*)lds, 16, 0, 0);
}

__device__ __forceinline__ float gelu_tanh(float v) {
    float u = 0.7978845608028654f * (v + 0.044715f * v * v * v);
    float e = __expf(2.0f * u);
    float t = 1.0f - 2.0f / (e + 1.0f);
    return 0.5f * v * (1.0f + t);
}

// ---------------------------------------------------------------- weight convert
__launch_bounds__(256)
__global__ void wconv_kernel(const float* __restrict__ W, f16* __restrict__ WT,
                             int K, int N) {
    __shared__ float t[32][33];
    int tx = threadIdx.x & 31, ty = threadIdx.x >> 5;
    int n0 = blockIdx.x * 32, k0 = blockIdx.y * 32;
    #pragma unroll
    for (int r = 0; r < 4; r++)
        t[ty * 4 + r][tx] = W[(size_t)(k0 + ty * 4 + r) * N + n0 + tx];
    __syncthreads();
    #pragma unroll
    for (int r = 0; r < 4; r++)
        WT[(size_t)(n0 + ty * 4 + r) * K + k0 + tx] = (f16)t[tx][ty * 4 + r];
}

// ---------------------------------------------------------------- LayerNorm -> f16
__launch_bounds__(256)
__global__ void ln_kernel(const float* __restrict__ x, const float* __restrict__ g,
                          const float* __restrict__ b, f16* __restrict__ y) {
    int row = blockIdx.x;
    int tid = threadIdx.x;
    const float* xr = x + (size_t)row * N_EMB;
    float4 v = *(const float4*)(xr + tid * 4);
    float s  = v.x + v.y + v.z + v.w;
    float sq = v.x * v.x + v.y * v.y + v.z * v.z + v.w * v.w;
    #pragma unroll
    for (int off = 32; off > 0; off >>= 1) {
        s  += __shfl_down(s, off);
        sq += __shfl_down(sq, off);
    }
    __shared__ float ws_[4], wq_[4];
    __shared__ float mean_s, rstd_s;
    int lane = tid & 63, wid = tid >> 6;
    if (lane == 0) { ws_[wid] = s; wq_[wid] = sq; }
    __syncthreads();
    if (tid == 0) {
        float st = ws_[0] + ws_[1] + ws_[2] + ws_[3];
        float qt = wq_[0] + wq_[1] + wq_[2] + wq_[3];
        float mu = st * (1.0f / N_EMB);
        float var = qt * (1.0f / N_EMB) - mu * mu;
        mean_s = mu;
        rstd_s = rsqrtf(var + 1e-5f);
    }
    __syncthreads();
    float mu = mean_s, r = rstd_s;
    float4 gv = *(const float4*)(g + tid * 4);
    float4 bv = *(const float4*)(b + tid * 4);
    f16x4 o;
    o.x = (f16)((v.x - mu) * r * gv.x + bv.x);
    o.y = (f16)((v.y - mu) * r * gv.y + bv.y);
    o.z = (f16)((v.z - mu) * r * gv.z + bv.z);
    o.w = (f16)((v.w - mu) * r * gv.w + bv.w);
    *(f16x4*)(y + (size_t)row * N_EMB + tid * 4) = o;
}

// ---------------------------------------------------------------- GEMM 8-phase
// EPI: 0 f32 | 1 f32 + f32 residual | 2 gelu->f16 | 3 qkv split
template <int EPI, int BM, int BN>
__launch_bounds__(512, 2)
__global__ void gemm8(const f16* __restrict__ A, const f16* __restrict__ Bt,
                      const float* __restrict__ bias, const float* __restrict__ res,
                      float* __restrict__ Cf, f16* __restrict__ Ch,
                      f16* __restrict__ vT, int K, int N) {
    constexpr int MI = BM / 32;          // m frags per wave (8 / 4)
    constexpr int MH = MI / 2;           // frags per m-half
    constexpr int NJ = BN / 64;          // n frags per wave (4)
    constexpr int AROUNDS = BM / 64;     // staging rounds for A (4 / 2)
    constexpr int BROUNDS = BN / 64;     // staging rounds for B (4)
    constexpr int ROUNDS = AROUNDS + BROUNDS;
    constexpr int P1E = (ROUNDS == 8) ? 3 : 2;   // stage-round split per phase
    constexpr int P2E = (ROUNDS == 8) ? 6 : 4;
    __shared__ f16 As[2][BM * 64];
    __shared__ f16 Bs[2][BN * 64];

    int tid = threadIdx.x;
    int lane = tid & 63, wave = tid >> 6;
    int wr = wave >> 2, wc = wave & 3;           // 2 x 4 wave grid
    int quad = lane >> 4, l16 = lane & 15;

    // bijective XCD swizzle (all grids divisible by 8)
    int nx = gridDim.x, nwg = nx * gridDim.y;
    int orig = blockIdx.y * nx + blockIdx.x;
    int cpx = nwg >> 3;
    int swz = (orig & 7) * cpx + (orig >> 3);
    int m0 = (swz / nx) * BM, n0 = (swz % nx) * BN;

    // staging: round r = 512 thr x 16B = 8KB = 64 rows of 128B.
    // phys granule (tid&7) of row srow holds logical granule (tid&7)^(srow&7).
    int srow = tid >> 3;                 // 0..63
    int sglog = (tid & 7) ^ (srow & 7);
    const f16* pa[AROUNDS];
    const f16* pb[BROUNDS];
    #pragma unroll
    for (int r = 0; r < AROUNDS; r++)
        pa[r] = A + (size_t)(m0 + r * 64 + srow) * K + sglog * 8;
    #pragma unroll
    for (int r = 0; r < BROUNDS; r++)
        pb[r] = Bt + (size_t)(n0 + r * 64 + srow) * K + sglog * 8;

    int nt = K >> 6;

    // stage round r of tile t into buffer buf
    auto stage = [&](int t, int buf, int r) {
        if (r < AROUNDS)
            async16((char*)As[buf] + (size_t)(r * 512 + tid) * 16,
                    pa[r] + (size_t)t * 64);
        else
            async16((char*)Bs[buf] + (size_t)((r - AROUNDS) * 512 + tid) * 16,
                    pb[r - AROUNDS] + (size_t)t * 64);
    };

    // prologue: tile 0 -> buf 0 (8 loads in flight)
    #pragma unroll
    for (int r = 0; r < ROUNDS; r++) stage(0, 0, r);

    f32x4 acc[MI][NJ] = {};
    for (int t = 0; t < nt; t++) {
        int p = t & 1;
        bool pf = (t + 1 < nt);

        // ---- tile entry: issue head of t+1 FIRST, then counted wait.
        // Outstanding: tile t's ROUNDS + P1E new -> vmcnt(P1E) waits for
        // exactly tile t's loads, keeps t+1's head in flight (T4).
        if (pf) {
            #pragma unroll
            for (int r = 0; r < P1E; r++) stage(t + 1, p ^ 1, r);
            if constexpr (ROUNDS == 8)
                asm volatile("s_waitcnt vmcnt(3)" ::: "memory");
            else
                asm volatile("s_waitcnt vmcnt(2)" ::: "memory");
        } else {
            asm volatile("s_waitcnt vmcnt(0)" ::: "memory");
        }
        __builtin_amdgcn_s_barrier();                     // tile t visible

        const f16* as = As[p];
        const f16* bs = Bs[p];
        f16x8 a0[MH], a1[MH], b0[NJ], b1[NJ];

        // ---- phase 1: quadrant (m-half 0, kstep 0)
        #pragma unroll
        for (int i = 0; i < MH; i++) {
            int row = wr * (BM / 2) + i * 16 + l16;
            a0[i] = *(const f16x8*)&as[row * 64 + ((quad) ^ (row & 7)) * 8];
        }
        #pragma unroll
        for (int j = 0; j < NJ; j++) {
            int row = wc * (BN / 4) + j * 16 + l16;
            b0[j] = *(const f16x8*)&bs[row * 64 + ((quad) ^ (row & 7)) * 8];
        }
        __builtin_amdgcn_s_barrier();
        asm volatile("s_waitcnt lgkmcnt(0)" ::: "memory");
        __builtin_amdgcn_s_setprio(1);
        #pragma unroll
        for (int i = 0; i < MH; i++) {
            #pragma unroll
            for (int j = 0; j < NJ; j++)
                acc[i][j] = __builtin_amdgcn_mfma_f32_16x16x32_f16(
                    a0[i], b0[j], acc[i][j], 0, 0, 0);
        }
        __builtin_amdgcn_s_setprio(0);
        __builtin_amdgcn_s_barrier();

        // ---- phase 2: quadrant (m-half 1, kstep 0)  [b0 held]
        #pragma unroll
        for (int i = 0; i < MH; i++) {
            int row = wr * (BM / 2) + (MH + i) * 16 + l16;
            a1[i] = *(const f16x8*)&as[row * 64 + ((quad) ^ (row & 7)) * 8];
        }
        if (pf) {
            #pragma unroll
            for (int r = P1E; r < P2E; r++) stage(t + 1, p ^ 1, r);
        }
        __builtin_amdgcn_s_barrier();
        asm volatile("s_waitcnt lgkmcnt(0)" ::: "memory");
        __builtin_amdgcn_s_setprio(1);
        #pragma unroll
        for (int i = 0; i < MH; i++) {
            #pragma unroll
            for (int j = 0; j < NJ; j++)
                acc[MH + i][j] = __builtin_amdgcn_mfma_f32_16x16x32_f16(
                    a1[i], b0[j], acc[MH + i][j], 0, 0, 0);
        }
        __builtin_amdgcn_s_setprio(0);
        __builtin_amdgcn_s_barrier();

        // ---- phase 3: quadrant (m-half 0, kstep 1)
        #pragma unroll
        for (int i = 0; i < MH; i++) {
            int row = wr * (BM / 2) + i * 16 + l16;
            a0[i] = *(const f16x8*)&as[row * 64 + ((4 + quad) ^ (row & 7)) * 8];
        }
        #pragma unroll
        for (int j = 0; j < NJ; j++) {
            int row = wc * (BN / 4) + j * 16 + l16;
            b1[j] = *(const f16x8*)&bs[row * 64 + ((4 + quad) ^ (row & 7)) * 8];
        }
        if (pf) {
            #pragma unroll
            for (int r = P2E; r < ROUNDS; r++) stage(t + 1, p ^ 1, r);
        }
        __builtin_amdgcn_s_barrier();
        asm volatile("s_waitcnt lgkmcnt(0)" ::: "memory");
        __builtin_amdgcn_s_setprio(1);
        #pragma unroll
        for (int i = 0; i < MH; i++) {
            #pragma unroll
            for (int j = 0; j < NJ; j++)
                acc[i][j] = __builtin_amdgcn_mfma_f32_16x16x32_f16(
                    a0[i], b1[j], acc[i][j], 0, 0, 0);
        }
        __builtin_amdgcn_s_setprio(0);
        __builtin_amdgcn_s_barrier();

        // ---- phase 4: quadrant (m-half 1, kstep 1)  [b1 held]
        #pragma unroll
        for (int i = 0; i < MH; i++) {
            int row = wr * (BM / 2) + (MH + i) * 16 + l16;
            a1[i] = *(const f16x8*)&as[row * 64 + ((4 + quad) ^ (row & 7)) * 8];
        }
        __builtin_amdgcn_s_barrier();
        asm volatile("s_waitcnt lgkmcnt(0)" ::: "memory");
        __builtin_amdgcn_s_setprio(1);
        #pragma unroll
        for (int i = 0; i < MH; i++) {
            #pragma unroll
            for (int j = 0; j < NJ; j++)
                acc[MH + i][j] = __builtin_amdgcn_mfma_f32_16x16x32_f16(
                    a1[i], b1[j], acc[MH + i][j], 0, 0, 0);
        }
        __builtin_amdgcn_s_setprio(0);
        __builtin_amdgcn_s_barrier();
    }

    // epilogue: C/D layout col=lane&15, row=quad*4+r
    #pragma unroll
    for (int i = 0; i < MI; i++) {
        int row0 = m0 + wr * (BM / 2) + i * 16 + quad * 4;
        #pragma unroll
        for (int j = 0; j < NJ; j++) {
            int col = n0 + wc * (BN / 4) + j * 16 + l16;
            float bb = bias[col];
            if (EPI == 3) {
                if (n0 < 2048) {
                    #pragma unroll
                    for (int r = 0; r < 4; r++)
                        Ch[(size_t)(row0 + r) * 2048 + col] = (f16)(acc[i][j][r] + bb);
                } else {
                    int hh = (col - 2048) >> 6, dd = col & 63;
                    int bb_ = row0 >> 11, t0 = row0 & 2047;
                    f16x4 pk;
                    pk.x = (f16)(acc[i][j][0] + bb);
                    pk.y = (f16)(acc[i][j][1] + bb);
                    pk.z = (f16)(acc[i][j][2] + bb);
                    pk.w = (f16)(acc[i][j][3] + bb);
                    *(f16x4*)(vT + ((size_t)(bb_ * 16 + hh) * 64 + dd) * 2048 + t0) = pk;
                }
            } else {
                #pragma unroll
                for (int r = 0; r < 4; r++) {
                    size_t idx = (size_t)(row0 + r) * N + col;
                    float v = acc[i][j][r] + bb;
                    if (EPI == 1) v += res[idx];
                    if (EPI == 2) Ch[idx] = (f16)gelu_tanh(v);
                    else          Cf[idx] = v;
                }
            }
        }
    }
}

// ---------------------------------------------------------------- MFMA flash
// 256 thr = 4 waves; 128 q-rows per tile (wave w owns 32), 128-wide j-tiles.
// Paired q-tiles (qt = 15-x then x): every block does 17 j-iterations.
__launch_bounds__(256, 2)
__global__ void flash_kernel(const f16* __restrict__ qk, const f16* __restrict__ vT,
                             f16* __restrict__ y) {
    __shared__ __align__(16) char smem[67584];
    f16* Ks = (f16*)smem;                      // [128 j][8 g of 8 d], g^=(j&7)
    f16* Vs = (f16*)(smem + 16384);            // [64 d][16 g of 8 j], g^=(d&7)
    int tid = threadIdx.x;
    int lane = tid & 63, w = tid >> 6;
    int quad = lane >> 4, l16 = lane & 15;
    f16* Ps = (f16*)(smem + 32768 + w * 8704); // per-wave [32 q][136 j]

    int bh = blockIdx.y;
    int b = bh >> 4, h = bh & 15;

    for (int half = 0; half < 2; half++) {
        int qt = half ? (int)blockIdx.x : 15 - (int)blockIdx.x;
        int q0 = qt * 128;

        f16x8 qf[2][2];
        #pragma unroll
        for (int qn = 0; qn < 2; qn++) {
            int q = q0 + w * 32 + qn * 16 + l16;
            #pragma unroll
            for (int dblk = 0; dblk < 2; dblk++) {
                f16x8 t = *(const f16x8*)(qk + (size_t)(b * T_SEQ + q) * 2048 +
                                          h * 64 + dblk * 32 + quad * 8);
                #pragma unroll
                for (int e = 0; e < 8; e++) t[e] = t[e] * (f16)0.125f;
                qf[qn][dblk] = t;
            }
        }

        float m_r[2] = {-INFINITY, -INFINITY};
        float l_r[2] = {0.0f, 0.0f};
        f32x4 Oacc[2][4] = {};

        for (int jt = 0; jt <= qt; jt++) {
            int j0 = jt * 128;
            __syncthreads();
            #pragma unroll
            for (int i = 0; i < 4; i++) {
                int L = i * 256 + tid;
                int j = L >> 3, g1 = L & 7;
                int g = g1 ^ (j & 7);
                async16((char*)Ks + (size_t)L * 16,
                        qk + (size_t)(b * T_SEQ + j0 + j) * 2048 + 1024 + h * 64 + g * 8);
            }
            #pragma unroll
            for (int i = 0; i < 4; i++) {
                int L = i * 256 + tid;
                int d = L >> 4, g1 = L & 15;
                int g = (g1 & 8) | ((g1 ^ d) & 7);
                async16((char*)Vs + (size_t)L * 16,
                        vT + ((size_t)(bh) * 64 + d) * 2048 + j0 + g * 8);
            }
            __syncthreads();

            f32x4 S[8][2];
            #pragma unroll
            for (int jm = 0; jm < 8; jm++) {
                f16x8 kf[2];
                #pragma unroll
                for (int dblk = 0; dblk < 2; dblk++) {
                    int j = jm * 16 + l16;
                    int g = (dblk * 4 + quad) ^ (j & 7);
                    kf[dblk] = *(const f16x8*)(Ks + (size_t)(j * 8 + g) * 8);
                }
                #pragma unroll
                for (int qn = 0; qn < 2; qn++) {
                    f32x4 s = {};
                    s = __builtin_amdgcn_mfma_f32_16x16x32_f16(kf[0], qf[qn][0], s, 0, 0, 0);
                    s = __builtin_amdgcn_mfma_f32_16x16x32_f16(kf[1], qf[qn][1], s, 0, 0, 0);
                    S[jm][qn] = s;
                }
            }

            if (jt == qt) {
                #pragma unroll
                for (int jm = 0; jm < 8; jm++)
                    #pragma unroll
                    for (int qn = 0; qn < 2; qn++)
                        #pragma unroll
                        for (int r = 0; r < 4; r++) {
                            int jl = jm * 16 + quad * 4 + r;
                            int ql = w * 32 + qn * 16 + l16;
                            if (jl > ql) S[jm][qn][r] = -1e30f;
                        }
            }

            float alpha[2];
            #pragma unroll
            for (int qn = 0; qn < 2; qn++) {
                float tmax = -INFINITY;
                #pragma unroll
                for (int jm = 0; jm < 8; jm++)
                    #pragma unroll
                    for (int r = 0; r < 4; r++)
                        tmax = fmaxf(tmax, S[jm][qn][r]);
                tmax = fmaxf(tmax, __shfl_xor(tmax, 16));
                tmax = fmaxf(tmax, __shfl_xor(tmax, 32));
                float mnew = fmaxf(m_r[qn], tmax);
                alpha[qn] = __expf(m_r[qn] - mnew);
                m_r[qn] = mnew;
                float rsum = 0.0f;
                #pragma unroll
                for (int jm = 0; jm < 8; jm++)
                    #pragma unroll
                    for (int r = 0; r < 4; r++) {
                        float p = __expf(S[jm][qn][r] - mnew);
                        S[jm][qn][r] = p;
                        rsum += p;
                    }
                rsum += __shfl_xor(rsum, 16);
                rsum += __shfl_xor(rsum, 32);
                l_r[qn] = l_r[qn] * alpha[qn] + rsum;
            }

            #pragma unroll
            for (int jm = 0; jm < 8; jm++)
                #pragma unroll
                for (int qn = 0; qn < 2; qn++) {
                    f16x4 pk;
                    pk.x = (f16)S[jm][qn][0];
                    pk.y = (f16)S[jm][qn][1];
                    pk.z = (f16)S[jm][qn][2];
                    pk.w = (f16)S[jm][qn][3];
                    *(f16x4*)(Ps + (size_t)(qn * 16 + l16) * 136 + jm * 16 + quad * 4) = pk;
                }

            float aPV[2][4];
            #pragma unroll
            for (int m = 0; m < 2; m++)
                #pragma unroll
                for (int r = 0; r < 4; r++)
                    aPV[m][r] = __shfl(alpha[m], quad * 20 + r);
            #pragma unroll
            for (int m = 0; m < 2; m++)
                #pragma unroll
                for (int n = 0; n < 4; n++)
                    #pragma unroll
                    for (int r = 0; r < 4; r++)
                        Oacc[m][n][r] *= aPV[m][r];

            #pragma unroll
            for (int kblk = 0; kblk < 4; kblk++) {
                f16x8 pf[2];
                #pragma unroll
                for (int m = 0; m < 2; m++)
                    pf[m] = *(const f16x8*)(Ps + (size_t)(m * 16 + l16) * 136 +
                                            kblk * 32 + quad * 8);
                f16x8 vf[4];
                #pragma unroll
                for (int n = 0; n < 4; n++) {
                    int d = n * 16 + l16;
                    int g = (kblk * 4 + quad);
                    int gs = (g & 8) | ((g ^ d) & 7);
                    vf[n] = *(const f16x8*)(Vs + (size_t)(d * 16 + gs) * 8);
                }
                #pragma unroll
                for (int m = 0; m < 2; m++)
                    #pragma unroll
                    for (int n = 0; n < 4; n++)
                        Oacc[m][n] = __builtin_amdgcn_mfma_f32_16x16x32_f16(
                            pf[m], vf[n], Oacc[m][n], 0, 0, 0);
            }
        }

        #pragma unroll
        for (int m = 0; m < 2; m++) {
            float lPV[4];
            #pragma unroll
            for (int r = 0; r < 4; r++)
                lPV[r] = 1.0f / __shfl(l_r[m], quad * 20 + r);
            #pragma unroll
            for (int n = 0; n < 4; n++) {
                #pragma unroll
                for (int r = 0; r < 4; r++) {
                    int q = q0 + w * 32 + m * 16 + quad * 4 + r;
                    y[(size_t)(b * T_SEQ + q) * N_EMB + h * 64 + n * 16 + l16] =
                        (f16)(Oacc[m][n][r] * lPV[r]);
                }
            }
        }
    }
}

// ---------------------------------------------------------------- launch
extern "C" void kernel_launch(void* const* d_in, const int* in_sizes, int n_in,
                              void* d_out, int out_size, void* d_ws, size_t ws_size,
                              hipStream_t stream) {
    const float* x      = (const float*)d_in[0];
    const float* ln1_g  = (const float*)d_in[1];
    const float* ln1_b  = (const float*)d_in[2];
    const float* w_attn = (const float*)d_in[3];
    const float* b_attn = (const float*)d_in[4];
    const float* w_proj = (const float*)d_in[5];
    const float* b_proj = (const float*)d_in[6];
    const float* ln2_g  = (const float*)d_in[7];
    const float* ln2_b  = (const float*)d_in[8];
    const float* w_fc   = (const float*)d_in[9];
    const float* b_fc   = (const float*)d_in[10];
    const float* w_fc2  = (const float*)d_in[11];
    const float* b_fc2  = (const float*)d_in[12];
    float* out = (float*)d_out;

    const size_t MB = 1024 * 1024;
    char* ws = (char*)d_ws;
    f16*   lnbuf = (f16*)ws;                        // 16 MB
    f16*   qkbuf = (f16*)(ws + 16 * MB);            // 32 MB: [M][2048] Q|K
    f16*   vTbuf = (f16*)(ws + 48 * MB);            // 16 MB: [b][h][d][t]
    f16*   ybuf  = (f16*)(ws + 64 * MB);            // 16 MB
    f16*   h     = (f16*)(ws + 80 * MB);            // 64 MB
    f16*   wT    = (f16*)(ws + 144 * MB);           // 26 MB
    f16* wT_attn = wT;
    f16* wT_proj = wT_attn + (size_t)3072 * 1024;
    f16* wT_fc   = wT_proj + (size_t)1024 * 1024;
    f16* wT_fc2  = wT_fc   + (size_t)1024 * 4096;

    wconv_kernel<<<dim3(3072 / 32, 1024 / 32), 256, 0, stream>>>(w_attn, wT_attn, 1024, 3072);
    wconv_kernel<<<dim3(1024 / 32, 1024 / 32), 256, 0, stream>>>(w_proj, wT_proj, 1024, 1024);
    wconv_kernel<<<dim3(4096 / 32, 1024 / 32), 256, 0, stream>>>(w_fc,   wT_fc,   1024, 4096);
    wconv_kernel<<<dim3(1024 / 32, 4096 / 32), 256, 0, stream>>>(w_fc2,  wT_fc2,  4096, 1024);

    ln_kernel<<<M_ROWS, 256, 0, stream>>>(x, ln1_g, ln1_b, lnbuf);
    gemm8<3, 256, 256><<<dim3(3072 / 256, M_ROWS / 256), 512, 0, stream>>>(
        lnbuf, wT_attn, b_attn, nullptr, nullptr, qkbuf, vTbuf, 1024, 3072);
    flash_kernel<<<dim3(8, 64), 256, 0, stream>>>(qkbuf, vTbuf, ybuf);
    gemm8<1, 128, 256><<<dim3(1024 / 256, M_ROWS / 128), 512, 0, stream>>>(
        ybuf, wT_proj, b_proj, x, out, nullptr, nullptr, 1024, 1024);
    ln_kernel<<<M_ROWS, 256, 0, stream>>>(out, ln2_g, ln2_b, lnbuf);
    gemm8<2, 256, 256><<<dim3(4096 / 256, M_ROWS / 256), 512, 0, stream>>>(
        lnbuf, wT_fc, b_fc, nullptr, nullptr, h, nullptr, 1024, 4096);
    gemm8<1, 128, 256><<<dim3(1024 / 256, M_ROWS / 128), 512, 0, stream>>>(
        h, wT_fc2, b_fc2, out, out, nullptr, nullptr, 4096, 1024);
}

// Round 9
// 532.927 us; speedup vs baseline: 1.1019x; 1.0252x over previous
//
#include <hip/hip_runtime.h>
#include <math.h>

// Round 12: fat phases for the 128-tile GEMMs. BM=128 (proj/fc2) now runs
// TWO phases per K-tile (one per k-step, 16 MFMA each = m201's proven
// cluster size) instead of four 8-MFMA quadrant phases (m230b's null
// quadrant). Barriers 9 -> 5 per K-tile. Counted vmcnt kept: entry issues 3
// staging rounds of t+1 then vmcnt(3); phase A issues the remaining 3.
// BM=256 path (qkv/fc, 16 MFMA/phase already) unchanged from round 11.
// Flash (paired q-tiles) / LN / wconv unchanged.
//
// ws: [0,16M) lnbuf | [16,48M) qk | [48,64M) vT | [64,80M) ybuf
//     [80,144M) h | [144,170M) wT

#define M_ROWS 8192
#define T_SEQ 2048
#define N_EMB 1024
#define N_HEADS 16
#define HEAD_D 64

typedef _Float16 f16;
typedef __attribute__((ext_vector_type(8))) _Float16 f16x8;
typedef __attribute__((ext_vector_type(4))) _Float16 f16x4;
typedef __attribute__((ext_vector_type(4))) float f32x4;

__device__ __forceinline__ void async16(void* lds, const void* g) {
    __builtin_amdgcn_global_load_lds(
        (const __attribute__((address_space(1))) unsigned int*)g,
        (__attribute__((address_space(3))) unsigned int*)lds, 16, 0, 0);
}

__device__ __forceinline__ float gelu_tanh(float v) {
    float u = 0.7978845608028654f * (v + 0.044715f * v * v * v);
    float e = __expf(2.0f * u);
    float t = 1.0f - 2.0f / (e + 1.0f);
    return 0.5f * v * (1.0f + t);
}

// ---------------------------------------------------------------- weight convert
__launch_bounds__(256)
__global__ void wconv_kernel(const float* __restrict__ W, f16* __restrict__ WT,
                             int K, int N) {
    __shared__ float t[32][33];
    int tx = threadIdx.x & 31, ty = threadIdx.x >> 5;
    int n0 = blockIdx.x * 32, k0 = blockIdx.y * 32;
    #pragma unroll
    for (int r = 0; r < 4; r++)
        t[ty * 4 + r][tx] = W[(size_t)(k0 + ty * 4 + r) * N + n0 + tx];
    __syncthreads();
    #pragma unroll
    for (int r = 0; r < 4; r++)
        WT[(size_t)(n0 + ty * 4 + r) * K + k0 + tx] = (f16)t[tx][ty * 4 + r];
}

// ---------------------------------------------------------------- LayerNorm -> f16
__launch_bounds__(256)
__global__ void ln_kernel(const float* __restrict__ x, const float* __restrict__ g,
                          const float* __restrict__ b, f16* __restrict__ y) {
    int row = blockIdx.x;
    int tid = threadIdx.x;
    const float* xr = x + (size_t)row * N_EMB;
    float4 v = *(const float4*)(xr + tid * 4);
    float s  = v.x + v.y + v.z + v.w;
    float sq = v.x * v.x + v.y * v.y + v.z * v.z + v.w * v.w;
    #pragma unroll
    for (int off = 32; off > 0; off >>= 1) {
        s  += __shfl_down(s, off);
        sq += __shfl_down(sq, off);
    }
    __shared__ float ws_[4], wq_[4];
    __shared__ float mean_s, rstd_s;
    int lane = tid & 63, wid = tid >> 6;
    if (lane == 0) { ws_[wid] = s; wq_[wid] = sq; }
    __syncthreads();
    if (tid == 0) {
        float st = ws_[0] + ws_[1] + ws_[2] + ws_[3];
        float qt = wq_[0] + wq_[1] + wq_[2] + wq_[3];
        float mu = st * (1.0f / N_EMB);
        float var = qt * (1.0f / N_EMB) - mu * mu;
        mean_s = mu;
        rstd_s = rsqrtf(var + 1e-5f);
    }
    __syncthreads();
    float mu = mean_s, r = rstd_s;
    float4 gv = *(const float4*)(g + tid * 4);
    float4 bv = *(const float4*)(b + tid * 4);
    f16x4 o;
    o.x = (f16)((v.x - mu) * r * gv.x + bv.x);
    o.y = (f16)((v.y - mu) * r * gv.y + bv.y);
    o.z = (f16)((v.z - mu) * r * gv.z + bv.z);
    o.w = (f16)((v.w - mu) * r * gv.w + bv.w);
    *(f16x4*)(y + (size_t)row * N_EMB + tid * 4) = o;
}

// ---------------------------------------------------------------- GEMM 8-phase
// EPI: 0 f32 | 1 f32 + f32 residual | 2 gelu->f16 | 3 qkv split
template <int EPI, int BM, int BN>
__launch_bounds__(512, 2)
__global__ void gemm8(const f16* __restrict__ A, const f16* __restrict__ Bt,
                      const float* __restrict__ bias, const float* __restrict__ res,
                      float* __restrict__ Cf, f16* __restrict__ Ch,
                      f16* __restrict__ vT, int K, int N) {
    constexpr int MI = BM / 32;          // m frags per wave (8 / 4)
    constexpr int MH = MI / 2;           // frags per m-half
    constexpr int NJ = BN / 64;          // n frags per wave (4)
    constexpr int AROUNDS = BM / 64;     // staging rounds for A (4 / 2)
    constexpr int BROUNDS = BN / 64;     // staging rounds for B (4)
    constexpr int ROUNDS = AROUNDS + BROUNDS;
    constexpr int P1E = 3;               // entry-issued stage rounds
    constexpr int P2E = (ROUNDS == 8) ? 6 : ROUNDS;
    __shared__ f16 As[2][BM * 64];
    __shared__ f16 Bs[2][BN * 64];

    int tid = threadIdx.x;
    int lane = tid & 63, wave = tid >> 6;
    int wr = wave >> 2, wc = wave & 3;           // 2 x 4 wave grid
    int quad = lane >> 4, l16 = lane & 15;

    // bijective XCD swizzle (all grids divisible by 8)
    int nx = gridDim.x, nwg = nx * gridDim.y;
    int orig = blockIdx.y * nx + blockIdx.x;
    int cpx = nwg >> 3;
    int swz = (orig & 7) * cpx + (orig >> 3);
    int m0 = (swz / nx) * BM, n0 = (swz % nx) * BN;

    // staging: round r = 512 thr x 16B = 8KB = 64 rows of 128B.
    // phys granule (tid&7) of row srow holds logical granule (tid&7)^(srow&7).
    int srow = tid >> 3;                 // 0..63
    int sglog = (tid & 7) ^ (srow & 7);
    const f16* pa[AROUNDS];
    const f16* pb[BROUNDS];
    #pragma unroll
    for (int r = 0; r < AROUNDS; r++)
        pa[r] = A + (size_t)(m0 + r * 64 + srow) * K + sglog * 8;
    #pragma unroll
    for (int r = 0; r < BROUNDS; r++)
        pb[r] = Bt + (size_t)(n0 + r * 64 + srow) * K + sglog * 8;

    int nt = K >> 6;

    // stage round r of tile t into buffer buf
    auto stage = [&](int t, int buf, int r) {
        if (r < AROUNDS)
            async16((char*)As[buf] + (size_t)(r * 512 + tid) * 16,
                    pa[r] + (size_t)t * 64);
        else
            async16((char*)Bs[buf] + (size_t)((r - AROUNDS) * 512 + tid) * 16,
                    pb[r - AROUNDS] + (size_t)t * 64);
    };

    // prologue: tile 0 -> buf 0
    #pragma unroll
    for (int r = 0; r < ROUNDS; r++) stage(0, 0, r);

    f32x4 acc[MI][NJ] = {};
    for (int t = 0; t < nt; t++) {
        int p = t & 1;
        bool pf = (t + 1 < nt);

        // ---- tile entry: issue head of t+1 FIRST, then counted wait (T4).
        if (pf) {
            #pragma unroll
            for (int r = 0; r < P1E; r++) stage(t + 1, p ^ 1, r);
            asm volatile("s_waitcnt vmcnt(3)" ::: "memory");
        } else {
            asm volatile("s_waitcnt vmcnt(0)" ::: "memory");
        }
        __builtin_amdgcn_s_barrier();                     // tile t visible

        const f16* as = As[p];
        const f16* bs = Bs[p];

        if constexpr (BM == 256) {
            // ---- 4 quadrant phases, 16 MFMA each (m201 granularity)
            f16x8 a0[MH], a1[MH], b0[NJ], b1[NJ];

            // phase 1: (m-half 0, kstep 0)
            #pragma unroll
            for (int i = 0; i < MH; i++) {
                int row = wr * (BM / 2) + i * 16 + l16;
                a0[i] = *(const f16x8*)&as[row * 64 + ((quad) ^ (row & 7)) * 8];
            }
            #pragma unroll
            for (int j = 0; j < NJ; j++) {
                int row = wc * (BN / 4) + j * 16 + l16;
                b0[j] = *(const f16x8*)&bs[row * 64 + ((quad) ^ (row & 7)) * 8];
            }
            __builtin_amdgcn_s_barrier();
            asm volatile("s_waitcnt lgkmcnt(0)" ::: "memory");
            __builtin_amdgcn_s_setprio(1);
            #pragma unroll
            for (int i = 0; i < MH; i++) {
                #pragma unroll
                for (int j = 0; j < NJ; j++)
                    acc[i][j] = __builtin_amdgcn_mfma_f32_16x16x32_f16(
                        a0[i], b0[j], acc[i][j], 0, 0, 0);
            }
            __builtin_amdgcn_s_setprio(0);
            __builtin_amdgcn_s_barrier();

            // phase 2: (m-half 1, kstep 0)  [b0 held]
            #pragma unroll
            for (int i = 0; i < MH; i++) {
                int row = wr * (BM / 2) + (MH + i) * 16 + l16;
                a1[i] = *(const f16x8*)&as[row * 64 + ((quad) ^ (row & 7)) * 8];
            }
            if (pf) {
                #pragma unroll
                for (int r = P1E; r < P2E; r++) stage(t + 1, p ^ 1, r);
            }
            __builtin_amdgcn_s_barrier();
            asm volatile("s_waitcnt lgkmcnt(0)" ::: "memory");
            __builtin_amdgcn_s_setprio(1);
            #pragma unroll
            for (int i = 0; i < MH; i++) {
                #pragma unroll
                for (int j = 0; j < NJ; j++)
                    acc[MH + i][j] = __builtin_amdgcn_mfma_f32_16x16x32_f16(
                        a1[i], b0[j], acc[MH + i][j], 0, 0, 0);
            }
            __builtin_amdgcn_s_setprio(0);
            __builtin_amdgcn_s_barrier();

            // phase 3: (m-half 0, kstep 1)
            #pragma unroll
            for (int i = 0; i < MH; i++) {
                int row = wr * (BM / 2) + i * 16 + l16;
                a0[i] = *(const f16x8*)&as[row * 64 + ((4 + quad) ^ (row & 7)) * 8];
            }
            #pragma unroll
            for (int j = 0; j < NJ; j++) {
                int row = wc * (BN / 4) + j * 16 + l16;
                b1[j] = *(const f16x8*)&bs[row * 64 + ((4 + quad) ^ (row & 7)) * 8];
            }
            if (pf) {
                #pragma unroll
                for (int r = P2E; r < ROUNDS; r++) stage(t + 1, p ^ 1, r);
            }
            __builtin_amdgcn_s_barrier();
            asm volatile("s_waitcnt lgkmcnt(0)" ::: "memory");
            __builtin_amdgcn_s_setprio(1);
            #pragma unroll
            for (int i = 0; i < MH; i++) {
                #pragma unroll
                for (int j = 0; j < NJ; j++)
                    acc[i][j] = __builtin_amdgcn_mfma_f32_16x16x32_f16(
                        a0[i], b1[j], acc[i][j], 0, 0, 0);
            }
            __builtin_amdgcn_s_setprio(0);
            __builtin_amdgcn_s_barrier();

            // phase 4: (m-half 1, kstep 1)  [b1 held]
            #pragma unroll
            for (int i = 0; i < MH; i++) {
                int row = wr * (BM / 2) + (MH + i) * 16 + l16;
                a1[i] = *(const f16x8*)&as[row * 64 + ((4 + quad) ^ (row & 7)) * 8];
            }
            __builtin_amdgcn_s_barrier();
            asm volatile("s_waitcnt lgkmcnt(0)" ::: "memory");
            __builtin_amdgcn_s_setprio(1);
            #pragma unroll
            for (int i = 0; i < MH; i++) {
                #pragma unroll
                for (int j = 0; j < NJ; j++)
                    acc[MH + i][j] = __builtin_amdgcn_mfma_f32_16x16x32_f16(
                        a1[i], b1[j], acc[MH + i][j], 0, 0, 0);
            }
            __builtin_amdgcn_s_setprio(0);
            __builtin_amdgcn_s_barrier();
        } else {
            // ---- BM=128: 2 fat phases per K-tile (one per kstep, 16 MFMA)
            f16x8 av[MI], bv[NJ];

            // phase A: kstep 0 — full MI x NJ
            #pragma unroll
            for (int i = 0; i < MI; i++) {
                int row = wr * (BM / 2) + i * 16 + l16;
                av[i] = *(const f16x8*)&as[row * 64 + ((quad) ^ (row & 7)) * 8];
            }
            #pragma unroll
            for (int j = 0; j < NJ; j++) {
                int row = wc * (BN / 4) + j * 16 + l16;
                bv[j] = *(const f16x8*)&bs[row * 64 + ((quad) ^ (row & 7)) * 8];
            }
            if (pf) {
                #pragma unroll
                for (int r = P1E; r < ROUNDS; r++) stage(t + 1, p ^ 1, r);
            }
            __builtin_amdgcn_s_barrier();
            asm volatile("s_waitcnt lgkmcnt(0)" ::: "memory");
            __builtin_amdgcn_s_setprio(1);
            #pragma unroll
            for (int i = 0; i < MI; i++) {
                #pragma unroll
                for (int j = 0; j < NJ; j++)
                    acc[i][j] = __builtin_amdgcn_mfma_f32_16x16x32_f16(
                        av[i], bv[j], acc[i][j], 0, 0, 0);
            }
            __builtin_amdgcn_s_setprio(0);
            __builtin_amdgcn_s_barrier();

            // phase B: kstep 1 — full MI x NJ
            #pragma unroll
            for (int i = 0; i < MI; i++) {
                int row = wr * (BM / 2) + i * 16 + l16;
                av[i] = *(const f16x8*)&as[row * 64 + ((4 + quad) ^ (row & 7)) * 8];
            }
            #pragma unroll
            for (int j = 0; j < NJ; j++) {
                int row = wc * (BN / 4) + j * 16 + l16;
                bv[j] = *(const f16x8*)&bs[row * 64 + ((4 + quad) ^ (row & 7)) * 8];
            }
            __builtin_amdgcn_s_barrier();
            asm volatile("s_waitcnt lgkmcnt(0)" ::: "memory");
            __builtin_amdgcn_s_setprio(1);
            #pragma unroll
            for (int i = 0; i < MI; i++) {
                #pragma unroll
                for (int j = 0; j < NJ; j++)
                    acc[i][j] = __builtin_amdgcn_mfma_f32_16x16x32_f16(
                        av[i], bv[j], acc[i][j], 0, 0, 0);
            }
            __builtin_amdgcn_s_setprio(0);
            __builtin_amdgcn_s_barrier();
        }
    }

    // epilogue: C/D layout col=lane&15, row=quad*4+r
    #pragma unroll
    for (int i = 0; i < MI; i++) {
        int row0 = m0 + wr * (BM / 2) + i * 16 + quad * 4;
        #pragma unroll
        for (int j = 0; j < NJ; j++) {
            int col = n0 + wc * (BN / 4) + j * 16 + l16;
            float bb = bias[col];
            if (EPI == 3) {
                if (n0 < 2048) {
                    #pragma unroll
                    for (int r = 0; r < 4; r++)
                        Ch[(size_t)(row0 + r) * 2048 + col] = (f16)(acc[i][j][r] + bb);
                } else {
                    int hh = (col - 2048) >> 6, dd = col & 63;
                    int bb_ = row0 >> 11, t0 = row0 & 2047;
                    f16x4 pk;
                    pk.x = (f16)(acc[i][j][0] + bb);
                    pk.y = (f16)(acc[i][j][1] + bb);
                    pk.z = (f16)(acc[i][j][2] + bb);
                    pk.w = (f16)(acc[i][j][3] + bb);
                    *(f16x4*)(vT + ((size_t)(bb_ * 16 + hh) * 64 + dd) * 2048 + t0) = pk;
                }
            } else {
                #pragma unroll
                for (int r = 0; r < 4; r++) {
                    size_t idx = (size_t)(row0 + r) * N + col;
                    float v = acc[i][j][r] + bb;
                    if (EPI == 1) v += res[idx];
                    if (EPI == 2) Ch[idx] = (f16)gelu_tanh(v);
                    else          Cf[idx] = v;
                }
            }
        }
    }
}

// ---------------------------------------------------------------- MFMA flash
// 256 thr = 4 waves; 128 q-rows per tile (wave w owns 32), 128-wide j-tiles.
// Paired q-tiles (qt = 15-x then x): every block does 17 j-iterations.
__launch_bounds__(256, 2)
__global__ void flash_kernel(const f16* __restrict__ qk, const f16* __restrict__ vT,
                             f16* __restrict__ y) {
    __shared__ __align__(16) char smem[67584];
    f16* Ks = (f16*)smem;                      // [128 j][8 g of 8 d], g^=(j&7)
    f16* Vs = (f16*)(smem + 16384);            // [64 d][16 g of 8 j], g^=(d&7)
    int tid = threadIdx.x;
    int lane = tid & 63, w = tid >> 6;
    int quad = lane >> 4, l16 = lane & 15;
    f16* Ps = (f16*)(smem + 32768 + w * 8704); // per-wave [32 q][136 j]

    int bh = blockIdx.y;
    int b = bh >> 4, h = bh & 15;

    for (int half = 0; half < 2; half++) {
        int qt = half ? (int)blockIdx.x : 15 - (int)blockIdx.x;
        int q0 = qt * 128;

        f16x8 qf[2][2];
        #pragma unroll
        for (int qn = 0; qn < 2; qn++) {
            int q = q0 + w * 32 + qn * 16 + l16;
            #pragma unroll
            for (int dblk = 0; dblk < 2; dblk++) {
                f16x8 t = *(const f16x8*)(qk + (size_t)(b * T_SEQ + q) * 2048 +
                                          h * 64 + dblk * 32 + quad * 8);
                #pragma unroll
                for (int e = 0; e < 8; e++) t[e] = t[e] * (f16)0.125f;
                qf[qn][dblk] = t;
            }
        }

        float m_r[2] = {-INFINITY, -INFINITY};
        float l_r[2] = {0.0f, 0.0f};
        f32x4 Oacc[2][4] = {};

        for (int jt = 0; jt <= qt; jt++) {
            int j0 = jt * 128;
            __syncthreads();
            #pragma unroll
            for (int i = 0; i < 4; i++) {
                int L = i * 256 + tid;
                int j = L >> 3, g1 = L & 7;
                int g = g1 ^ (j & 7);
                async16((char*)Ks + (size_t)L * 16,
                        qk + (size_t)(b * T_SEQ + j0 + j) * 2048 + 1024 + h * 64 + g * 8);
            }
            #pragma unroll
            for (int i = 0; i < 4; i++) {
                int L = i * 256 + tid;
                int d = L >> 4, g1 = L & 15;
                int g = (g1 & 8) | ((g1 ^ d) & 7);
                async16((char*)Vs + (size_t)L * 16,
                        vT + ((size_t)(bh) * 64 + d) * 2048 + j0 + g * 8);
            }
            __syncthreads();

            f32x4 S[8][2];
            #pragma unroll
            for (int jm = 0; jm < 8; jm++) {
                f16x8 kf[2];
                #pragma unroll
                for (int dblk = 0; dblk < 2; dblk++) {
                    int j = jm * 16 + l16;
                    int g = (dblk * 4 + quad) ^ (j & 7);
                    kf[dblk] = *(const f16x8*)(Ks + (size_t)(j * 8 + g) * 8);
                }
                #pragma unroll
                for (int qn = 0; qn < 2; qn++) {
                    f32x4 s = {};
                    s = __builtin_amdgcn_mfma_f32_16x16x32_f16(kf[0], qf[qn][0], s, 0, 0, 0);
                    s = __builtin_amdgcn_mfma_f32_16x16x32_f16(kf[1], qf[qn][1], s, 0, 0, 0);
                    S[jm][qn] = s;
                }
            }

            if (jt == qt) {
                #pragma unroll
                for (int jm = 0; jm < 8; jm++)
                    #pragma unroll
                    for (int qn = 0; qn < 2; qn++)
                        #pragma unroll
                        for (int r = 0; r < 4; r++) {
                            int jl = jm * 16 + quad * 4 + r;
                            int ql = w * 32 + qn * 16 + l16;
                            if (jl > ql) S[jm][qn][r] = -1e30f;
                        }
            }

            float alpha[2];
            #pragma unroll
            for (int qn = 0; qn < 2; qn++) {
                float tmax = -INFINITY;
                #pragma unroll
                for (int jm = 0; jm < 8; jm++)
                    #pragma unroll
                    for (int r = 0; r < 4; r++)
                        tmax = fmaxf(tmax, S[jm][qn][r]);
                tmax = fmaxf(tmax, __shfl_xor(tmax, 16));
                tmax = fmaxf(tmax, __shfl_xor(tmax, 32));
                float mnew = fmaxf(m_r[qn], tmax);
                alpha[qn] = __expf(m_r[qn] - mnew);
                m_r[qn] = mnew;
                float rsum = 0.0f;
                #pragma unroll
                for (int jm = 0; jm < 8; jm++)
                    #pragma unroll
                    for (int r = 0; r < 4; r++) {
                        float p = __expf(S[jm][qn][r] - mnew);
                        S[jm][qn][r] = p;
                        rsum += p;
                    }
                rsum += __shfl_xor(rsum, 16);
                rsum += __shfl_xor(rsum, 32);
                l_r[qn] = l_r[qn] * alpha[qn] + rsum;
            }

            #pragma unroll
            for (int jm = 0; jm < 8; jm++)
                #pragma unroll
                for (int qn = 0; qn < 2; qn++) {
                    f16x4 pk;
                    pk.x = (f16)S[jm][qn][0];
                    pk.y = (f16)S[jm][qn][1];
                    pk.z = (f16)S[jm][qn][2];
                    pk.w = (f16)S[jm][qn][3];
                    *(f16x4*)(Ps + (size_t)(qn * 16 + l16) * 136 + jm * 16 + quad * 4) = pk;
                }

            float aPV[2][4];
            #pragma unroll
            for (int m = 0; m < 2; m++)
                #pragma unroll
                for (int r = 0; r < 4; r++)
                    aPV[m][r] = __shfl(alpha[m], quad * 20 + r);
            #pragma unroll
            for (int m = 0; m < 2; m++)
                #pragma unroll
                for (int n = 0; n < 4; n++)
                    #pragma unroll
                    for (int r = 0; r < 4; r++)
                        Oacc[m][n][r] *= aPV[m][r];

            #pragma unroll
            for (int kblk = 0; kblk < 4; kblk++) {
                f16x8 pf[2];
                #pragma unroll
                for (int m = 0; m < 2; m++)
                    pf[m] = *(const f16x8*)(Ps + (size_t)(m * 16 + l16) * 136 +
                                            kblk * 32 + quad * 8);
                f16x8 vf[4];
                #pragma unroll
                for (int n = 0; n < 4; n++) {
                    int d = n * 16 + l16;
                    int g = (kblk * 4 + quad);
                    int gs = (g & 8) | ((g ^ d) & 7);
                    vf[n] = *(const f16x8*)(Vs + (size_t)(d * 16 + gs) * 8);
                }
                #pragma unroll
                for (int m = 0; m < 2; m++)
                    #pragma unroll
                    for (int n = 0; n < 4; n++)
                        Oacc[m][n] = __builtin_amdgcn_mfma_f32_16x16x32_f16(
                            pf[m], vf[n], Oacc[m][n], 0, 0, 0);
            }
        }

        #pragma unroll
        for (int m = 0; m < 2; m++) {
            float lPV[4];
            #pragma unroll
            for (int r = 0; r < 4; r++)
                lPV[r] = 1.0f / __shfl(l_r[m], quad * 20 + r);
            #pragma unroll
            for (int n = 0; n < 4; n++) {
                #pragma unroll
                for (int r = 0; r < 4; r++) {
                    int q = q0 + w * 32 + m * 16 + quad * 4 + r;
                    y[(size_t)(b * T_SEQ + q) * N_EMB + h * 64 + n * 16 + l16] =
                        (f16)(Oacc[m][n][r] * lPV[r]);
                }
            }
        }
    }
}

// ---------------------------------------------------------------- launch
extern "C" void kernel_launch(void* const* d_in, const int* in_sizes, int n_in,
                              void* d_out, int out_size, void* d_ws, size_t ws_size,
                              hipStream_t stream) {
    const float* x      = (const float*)d_in[0];
    const float* ln1_g  = (const float*)d_in[1];
    const float* ln1_b  = (const float*)d_in[2];
    const float* w_attn = (const float*)d_in[3];
    const float* b_attn = (const float*)d_in[4];
    const float* w_proj = (const float*)d_in[5];
    const float* b_proj = (const float*)d_in[6];
    const float* ln2_g  = (const float*)d_in[7];
    const float* ln2_b  = (const float*)d_in[8];
    const float* w_fc   = (const float*)d_in[9];
    const float* b_fc   = (const float*)d_in[10];
    const float* w_fc2  = (const float*)d_in[11];
    const float* b_fc2  = (const float*)d_in[12];
    float* out = (float*)d_out;

    const size_t MB = 1024 * 1024;
    char* ws = (char*)d_ws;
    f16*   lnbuf = (f16*)ws;                        // 16 MB
    f16*   qkbuf = (f16*)(ws + 16 * MB);            // 32 MB: [M][2048] Q|K
    f16*   vTbuf = (f16*)(ws + 48 * MB);            // 16 MB: [b][h][d][t]
    f16*   ybuf  = (f16*)(ws + 64 * MB);            // 16 MB
    f16*   h     = (f16*)(ws + 80 * MB);            // 64 MB
    f16*   wT    = (f16*)(ws + 144 * MB);           // 26 MB
    f16* wT_attn = wT;
    f16* wT_proj = wT_attn + (size_t)3072 * 1024;
    f16* wT_fc   = wT_proj + (size_t)1024 * 1024;
    f16* wT_fc2  = wT_fc   + (size_t)1024 * 4096;

    wconv_kernel<<<dim3(3072 / 32, 1024 / 32), 256, 0, stream>>>(w_attn, wT_attn, 1024, 3072);
    wconv_kernel<<<dim3(1024 / 32, 1024 / 32), 256, 0, stream>>>(w_proj, wT_proj, 1024, 1024);
    wconv_kernel<<<dim3(4096 / 32, 1024 / 32), 256, 0, stream>>>(w_fc,   wT_fc,   1024, 4096);
    wconv_kernel<<<dim3(1024 / 32, 4096 / 32), 256, 0, stream>>>(w_fc2,  wT_fc2,  4096, 1024);

    ln_kernel<<<M_ROWS, 256, 0, stream>>>(x, ln1_g, ln1_b, lnbuf);
    gemm8<3, 256, 256><<<dim3(3072 / 256, M_ROWS / 256), 512, 0, stream>>>(
        lnbuf, wT_attn, b_attn, nullptr, nullptr, qkbuf, vTbuf, 1024, 3072);
    flash_kernel<<<dim3(8, 64), 256, 0, stream>>>(qkbuf, vTbuf, ybuf);
    gemm8<1, 128, 256><<<dim3(1024 / 256, M_ROWS / 128), 512, 0, stream>>>(
        ybuf, wT_proj, b_proj, x, out, nullptr, nullptr, 1024, 1024);
    ln_kernel<<<M_ROWS, 256, 0, stream>>>(out, ln2_g, ln2_b, lnbuf);
    gemm8<2, 256, 256><<<dim3(4096 / 256, M_ROWS / 256), 512, 0, stream>>>(
        lnbuf, wT_fc, b_fc, nullptr, nullptr, h, nullptr, 1024, 4096);
    gemm8<1, 128, 256><<<dim3(1024 / 256, M_ROWS / 128), 512, 0, stream>>>(
        h, wT_fc2, b_fc2, out, out, nullptr, nullptr, 4096, 1024);
}

// Round 10
// 511.372 us; speedup vs baseline: 1.1483x; 1.0421x over previous
//
#include <hip/hip_runtime.h>
#include <math.h>

// Round 13: cross-block overlap for fc & qkv. gemmX: 128x256 tile, 512 thr,
// 8 waves (2Mx4N, wave 64x64), BK=32, 48 KB dbuf LDS -> 2-3 blocks/CU
// (launch_bounds(512,4) caps VGPR at 128; acc[4][4]=64). Simple 2-barrier
// loop; counted vmcnt (entry issues t+1's 3 staging rounds then vmcnt(3)).
// Block A's LDS-read/barrier phases overlap block B's MFMA on the same CU
// (m114 co-scheduling) — replaces the failed 1-block/CU deep pipelines.
// proj/fc2 keep round-12 gemm8<1,128,256> fat-phase config. Flash/LN/wconv
// unchanged.
//
// ws: [0,16M) lnbuf | [16,48M) qk | [48,64M) vT | [64,80M) ybuf
//     [80,144M) h | [144,170M) wT

#define M_ROWS 8192
#define T_SEQ 2048
#define N_EMB 1024
#define N_HEADS 16
#define HEAD_D 64

typedef _Float16 f16;
typedef __attribute__((ext_vector_type(8))) _Float16 f16x8;
typedef __attribute__((ext_vector_type(4))) _Float16 f16x4;
typedef __attribute__((ext_vector_type(4))) float f32x4;

__device__ __forceinline__ void async16(void* lds, const void* g) {
    __builtin_amdgcn_global_load_lds(
        (const __attribute__((address_space(1))) unsigned int*)g,
        (__attribute__((address_space(3))) unsigned int*)lds, 16, 0, 0);
}

__device__ __forceinline__ float gelu_tanh(float v) {
    float u = 0.7978845608028654f * (v + 0.044715f * v * v * v);
    float e = __expf(2.0f * u);
    float t = 1.0f - 2.0f / (e + 1.0f);
    return 0.5f * v * (1.0f + t);
}

// ---------------------------------------------------------------- weight convert
__launch_bounds__(256)
__global__ void wconv_kernel(const float* __restrict__ W, f16* __restrict__ WT,
                             int K, int N) {
    __shared__ float t[32][33];
    int tx = threadIdx.x & 31, ty = threadIdx.x >> 5;
    int n0 = blockIdx.x * 32, k0 = blockIdx.y * 32;
    #pragma unroll
    for (int r = 0; r < 4; r++)
        t[ty * 4 + r][tx] = W[(size_t)(k0 + ty * 4 + r) * N + n0 + tx];
    __syncthreads();
    #pragma unroll
    for (int r = 0; r < 4; r++)
        WT[(size_t)(n0 + ty * 4 + r) * K + k0 + tx] = (f16)t[tx][ty * 4 + r];
}

// ---------------------------------------------------------------- LayerNorm -> f16
__launch_bounds__(256)
__global__ void ln_kernel(const float* __restrict__ x, const float* __restrict__ g,
                          const float* __restrict__ b, f16* __restrict__ y) {
    int row = blockIdx.x;
    int tid = threadIdx.x;
    const float* xr = x + (size_t)row * N_EMB;
    float4 v = *(const float4*)(xr + tid * 4);
    float s  = v.x + v.y + v.z + v.w;
    float sq = v.x * v.x + v.y * v.y + v.z * v.z + v.w * v.w;
    #pragma unroll
    for (int off = 32; off > 0; off >>= 1) {
        s  += __shfl_down(s, off);
        sq += __shfl_down(sq, off);
    }
    __shared__ float ws_[4], wq_[4];
    __shared__ float mean_s, rstd_s;
    int lane = tid & 63, wid = tid >> 6;
    if (lane == 0) { ws_[wid] = s; wq_[wid] = sq; }
    __syncthreads();
    if (tid == 0) {
        float st = ws_[0] + ws_[1] + ws_[2] + ws_[3];
        float qt = wq_[0] + wq_[1] + wq_[2] + wq_[3];
        float mu = st * (1.0f / N_EMB);
        float var = qt * (1.0f / N_EMB) - mu * mu;
        mean_s = mu;
        rstd_s = rsqrtf(var + 1e-5f);
    }
    __syncthreads();
    float mu = mean_s, r = rstd_s;
    float4 gv = *(const float4*)(g + tid * 4);
    float4 bv = *(const float4*)(b + tid * 4);
    f16x4 o;
    o.x = (f16)((v.x - mu) * r * gv.x + bv.x);
    o.y = (f16)((v.y - mu) * r * gv.y + bv.y);
    o.z = (f16)((v.z - mu) * r * gv.z + bv.z);
    o.w = (f16)((v.w - mu) * r * gv.w + bv.w);
    *(f16x4*)(y + (size_t)row * N_EMB + tid * 4) = o;
}

// ---------------------------------------------------------------- gemmX
// 128x256 tile, 512 thr, 8 waves 2x4 (wave 64x64), BK=32, dbuf 48 KB LDS,
// 2-3 blocks/CU. Per K-tile: {entry: stage(t+1) x3; vmcnt(3); barrier;
// 8 ds_read_b128; lgkmcnt(0); setprio(1) 16 MFMA setprio(0); barrier}.
// Swizzle: phys granule = logical ^ ((row>>1)&3) (rows 64 B at BK=32) —
// round 9's measured-zero-conflict involution.
// EPI: 2 gelu->f16 | 3 qkv split
template <int EPI>
__launch_bounds__(512, 4)
__global__ void gemmX(const f16* __restrict__ A, const f16* __restrict__ Bt,
                      const float* __restrict__ bias,
                      float* __restrict__ Cf, f16* __restrict__ Ch,
                      f16* __restrict__ vT, int K, int N) {
    __shared__ f16 As[2][128 * 32];    // 16 KB
    __shared__ f16 Bs[2][256 * 32];    // 32 KB
    int tid = threadIdx.x;
    int lane = tid & 63, wave = tid >> 6;
    int wr = wave >> 2, wc = wave & 3;         // 2 x 4 wave grid
    int quad = lane >> 4, l16 = lane & 15;

    // bijective XCD swizzle (grids divisible by 8)
    int nx = gridDim.x, nwg = nx * gridDim.y;
    int orig = blockIdx.y * nx + blockIdx.x;
    int cpx = nwg >> 3;
    int swz = (orig & 7) * cpx + (orig >> 3);
    int m0 = (swz / nx) * 128, n0 = (swz % nx) * 256;

    // staging: one round = 512 thr x 16 B = 8 KB = 128 rows of 64 B.
    // phys granule (tid&3) of row srow holds logical (tid&3)^((srow>>1)&3).
    int srow = tid >> 2;                       // 0..127
    int sg = (tid & 3) ^ ((srow >> 1) & 3);
    const f16* pA  = A  + (size_t)(m0 + srow) * K + sg * 8;
    const f16* pB0 = Bt + (size_t)(n0 + srow) * K + sg * 8;
    const f16* pB1 = Bt + (size_t)(n0 + 128 + srow) * K + sg * 8;
    char* dA  = (char*)As + (size_t)tid * 16;
    char* dB0 = (char*)Bs + (size_t)tid * 16;
    char* dB1 = (char*)Bs + (size_t)(512 + tid) * 16;

    int nt = K >> 5;

    auto stage = [&](int t, int buf) {
        async16(dA  + buf * 8192,  pA  + (size_t)t * 32);
        async16(dB0 + buf * 16384, pB0 + (size_t)t * 32);
        async16(dB1 + buf * 16384, pB1 + (size_t)t * 32);
    };

    // prologue: tile 0 -> buf 0 (3 loads in flight)
    stage(0, 0);

    f32x4 acc[4][4] = {};
    for (int t = 0; t < nt; t++) {
        int p = t & 1;
        if (t + 1 < nt) {
            stage(t + 1, p ^ 1);               // outstanding: 3(t) + 3(t+1)
            asm volatile("s_waitcnt vmcnt(3)" ::: "memory");   // t landed
        } else {
            asm volatile("s_waitcnt vmcnt(0)" ::: "memory");
        }
        __builtin_amdgcn_s_barrier();          // tile t visible to all waves

        const f16* as = As[p];
        const f16* bs = Bs[p];
        f16x8 av[4], bv[4];
        #pragma unroll
        for (int i = 0; i < 4; i++) {
            int row = wr * 64 + i * 16 + l16;
            av[i] = *(const f16x8*)&as[row * 32 + (quad ^ ((row >> 1) & 3)) * 8];
        }
        #pragma unroll
        for (int j = 0; j < 4; j++) {
            int row = wc * 64 + j * 16 + l16;
            bv[j] = *(const f16x8*)&bs[row * 32 + (quad ^ ((row >> 1) & 3)) * 8];
        }
        asm volatile("s_waitcnt lgkmcnt(0)" ::: "memory");
        __builtin_amdgcn_s_setprio(1);
        #pragma unroll
        for (int i = 0; i < 4; i++) {
            #pragma unroll
            for (int j = 0; j < 4; j++)
                acc[i][j] = __builtin_amdgcn_mfma_f32_16x16x32_f16(
                    av[i], bv[j], acc[i][j], 0, 0, 0);
        }
        __builtin_amdgcn_s_setprio(0);
        __builtin_amdgcn_s_barrier();          // reads of buf p retired
    }

    // epilogue: C/D layout col=lane&15, row=quad*4+r
    #pragma unroll
    for (int i = 0; i < 4; i++) {
        int row0 = m0 + wr * 64 + i * 16 + quad * 4;
        #pragma unroll
        for (int j = 0; j < 4; j++) {
            int col = n0 + wc * 64 + j * 16 + l16;
            float bb = bias[col];
            if (EPI == 3) {
                if (n0 < 2048) {
                    #pragma unroll
                    for (int r = 0; r < 4; r++)
                        Ch[(size_t)(row0 + r) * 2048 + col] = (f16)(acc[i][j][r] + bb);
                } else {
                    int hh = (col - 2048) >> 6, dd = col & 63;
                    int bb_ = row0 >> 11, t0 = row0 & 2047;
                    f16x4 pk;
                    pk.x = (f16)(acc[i][j][0] + bb);
                    pk.y = (f16)(acc[i][j][1] + bb);
                    pk.z = (f16)(acc[i][j][2] + bb);
                    pk.w = (f16)(acc[i][j][3] + bb);
                    *(f16x4*)(vT + ((size_t)(bb_ * 16 + hh) * 64 + dd) * 2048 + t0) = pk;
                }
            } else {
                #pragma unroll
                for (int r = 0; r < 4; r++) {
                    size_t idx = (size_t)(row0 + r) * N + col;
                    Ch[idx] = (f16)gelu_tanh(acc[i][j][r] + bb);
                }
            }
        }
    }
}

// ---------------------------------------------------------------- gemm8 (proj/fc2)
// BM=128, BN=256: 2 fat phases per K-tile (16 MFMA each), counted vmcnt.
// EPI: 1 f32 + f32 residual
template <int EPI, int BM, int BN>
__launch_bounds__(512, 2)
__global__ void gemm8(const f16* __restrict__ A, const f16* __restrict__ Bt,
                      const float* __restrict__ bias, const float* __restrict__ res,
                      float* __restrict__ Cf, int K, int N) {
    constexpr int MI = BM / 32;
    constexpr int NJ = BN / 64;
    constexpr int AROUNDS = BM / 64;
    constexpr int BROUNDS = BN / 64;
    constexpr int ROUNDS = AROUNDS + BROUNDS;
    constexpr int P1E = 3;
    __shared__ f16 As[2][BM * 64];
    __shared__ f16 Bs[2][BN * 64];

    int tid = threadIdx.x;
    int lane = tid & 63, wave = tid >> 6;
    int wr = wave >> 2, wc = wave & 3;
    int quad = lane >> 4, l16 = lane & 15;

    int nx = gridDim.x, nwg = nx * gridDim.y;
    int orig = blockIdx.y * nx + blockIdx.x;
    int cpx = nwg >> 3;
    int swz = (orig & 7) * cpx + (orig >> 3);
    int m0 = (swz / nx) * BM, n0 = (swz % nx) * BN;

    int srow = tid >> 3;
    int sglog = (tid & 7) ^ (srow & 7);
    const f16* pa[AROUNDS];
    const f16* pb[BROUNDS];
    #pragma unroll
    for (int r = 0; r < AROUNDS; r++)
        pa[r] = A + (size_t)(m0 + r * 64 + srow) * K + sglog * 8;
    #pragma unroll
    for (int r = 0; r < BROUNDS; r++)
        pb[r] = Bt + (size_t)(n0 + r * 64 + srow) * K + sglog * 8;

    int nt = K >> 6;

    auto stage = [&](int t, int buf, int r) {
        if (r < AROUNDS)
            async16((char*)As[buf] + (size_t)(r * 512 + tid) * 16,
                    pa[r] + (size_t)t * 64);
        else
            async16((char*)Bs[buf] + (size_t)((r - AROUNDS) * 512 + tid) * 16,
                    pb[r - AROUNDS] + (size_t)t * 64);
    };

    #pragma unroll
    for (int r = 0; r < ROUNDS; r++) stage(0, 0, r);

    f32x4 acc[MI][NJ] = {};
    for (int t = 0; t < nt; t++) {
        int p = t & 1;
        bool pf = (t + 1 < nt);

        if (pf) {
            #pragma unroll
            for (int r = 0; r < P1E; r++) stage(t + 1, p ^ 1, r);
            asm volatile("s_waitcnt vmcnt(3)" ::: "memory");
        } else {
            asm volatile("s_waitcnt vmcnt(0)" ::: "memory");
        }
        __builtin_amdgcn_s_barrier();

        const f16* as = As[p];
        const f16* bs = Bs[p];
        f16x8 av[MI], bv[NJ];

        // phase A: kstep 0
        #pragma unroll
        for (int i = 0; i < MI; i++) {
            int row = wr * (BM / 2) + i * 16 + l16;
            av[i] = *(const f16x8*)&as[row * 64 + ((quad) ^ (row & 7)) * 8];
        }
        #pragma unroll
        for (int j = 0; j < NJ; j++) {
            int row = wc * (BN / 4) + j * 16 + l16;
            bv[j] = *(const f16x8*)&bs[row * 64 + ((quad) ^ (row & 7)) * 8];
        }
        if (pf) {
            #pragma unroll
            for (int r = P1E; r < ROUNDS; r++) stage(t + 1, p ^ 1, r);
        }
        __builtin_amdgcn_s_barrier();
        asm volatile("s_waitcnt lgkmcnt(0)" ::: "memory");
        __builtin_amdgcn_s_setprio(1);
        #pragma unroll
        for (int i = 0; i < MI; i++) {
            #pragma unroll
            for (int j = 0; j < NJ; j++)
                acc[i][j] = __builtin_amdgcn_mfma_f32_16x16x32_f16(
                    av[i], bv[j], acc[i][j], 0, 0, 0);
        }
        __builtin_amdgcn_s_setprio(0);
        __builtin_amdgcn_s_barrier();

        // phase B: kstep 1
        #pragma unroll
        for (int i = 0; i < MI; i++) {
            int row = wr * (BM / 2) + i * 16 + l16;
            av[i] = *(const f16x8*)&as[row * 64 + ((4 + quad) ^ (row & 7)) * 8];
        }
        #pragma unroll
        for (int j = 0; j < NJ; j++) {
            int row = wc * (BN / 4) + j * 16 + l16;
            bv[j] = *(const f16x8*)&bs[row * 64 + ((4 + quad) ^ (row & 7)) * 8];
        }
        __builtin_amdgcn_s_barrier();
        asm volatile("s_waitcnt lgkmcnt(0)" ::: "memory");
        __builtin_amdgcn_s_setprio(1);
        #pragma unroll
        for (int i = 0; i < MI; i++) {
            #pragma unroll
            for (int j = 0; j < NJ; j++)
                acc[i][j] = __builtin_amdgcn_mfma_f32_16x16x32_f16(
                    av[i], bv[j], acc[i][j], 0, 0, 0);
        }
        __builtin_amdgcn_s_setprio(0);
        __builtin_amdgcn_s_barrier();
    }

    #pragma unroll
    for (int i = 0; i < MI; i++) {
        int row0 = m0 + wr * (BM / 2) + i * 16 + quad * 4;
        #pragma unroll
        for (int j = 0; j < NJ; j++) {
            int col = n0 + wc * (BN / 4) + j * 16 + l16;
            float bb = bias[col];
            #pragma unroll
            for (int r = 0; r < 4; r++) {
                size_t idx = (size_t)(row0 + r) * N + col;
                Cf[idx] = acc[i][j][r] + bb + res[idx];
            }
        }
    }
}

// ---------------------------------------------------------------- MFMA flash
// 256 thr = 4 waves; 128 q-rows per tile (wave w owns 32), 128-wide j-tiles.
// Paired q-tiles (qt = 15-x then x): every block does 17 j-iterations.
__launch_bounds__(256, 2)
__global__ void flash_kernel(const f16* __restrict__ qk, const f16* __restrict__ vT,
                             f16* __restrict__ y) {
    __shared__ __align__(16) char smem[67584];
    f16* Ks = (f16*)smem;                      // [128 j][8 g of 8 d], g^=(j&7)
    f16* Vs = (f16*)(smem + 16384);            // [64 d][16 g of 8 j], g^=(d&7)
    int tid = threadIdx.x;
    int lane = tid & 63, w = tid >> 6;
    int quad = lane >> 4, l16 = lane & 15;
    f16* Ps = (f16*)(smem + 32768 + w * 8704); // per-wave [32 q][136 j]

    int bh = blockIdx.y;
    int b = bh >> 4, h = bh & 15;

    for (int half = 0; half < 2; half++) {
        int qt = half ? (int)blockIdx.x : 15 - (int)blockIdx.x;
        int q0 = qt * 128;

        f16x8 qf[2][2];
        #pragma unroll
        for (int qn = 0; qn < 2; qn++) {
            int q = q0 + w * 32 + qn * 16 + l16;
            #pragma unroll
            for (int dblk = 0; dblk < 2; dblk++) {
                f16x8 t = *(const f16x8*)(qk + (size_t)(b * T_SEQ + q) * 2048 +
                                          h * 64 + dblk * 32 + quad * 8);
                #pragma unroll
                for (int e = 0; e < 8; e++) t[e] = t[e] * (f16)0.125f;
                qf[qn][dblk] = t;
            }
        }

        float m_r[2] = {-INFINITY, -INFINITY};
        float l_r[2] = {0.0f, 0.0f};
        f32x4 Oacc[2][4] = {};

        for (int jt = 0; jt <= qt; jt++) {
            int j0 = jt * 128;
            __syncthreads();
            #pragma unroll
            for (int i = 0; i < 4; i++) {
                int L = i * 256 + tid;
                int j = L >> 3, g1 = L & 7;
                int g = g1 ^ (j & 7);
                async16((char*)Ks + (size_t)L * 16,
                        qk + (size_t)(b * T_SEQ + j0 + j) * 2048 + 1024 + h * 64 + g * 8);
            }
            #pragma unroll
            for (int i = 0; i < 4; i++) {
                int L = i * 256 + tid;
                int d = L >> 4, g1 = L & 15;
                int g = (g1 & 8) | ((g1 ^ d) & 7);
                async16((char*)Vs + (size_t)L * 16,
                        vT + ((size_t)(bh) * 64 + d) * 2048 + j0 + g * 8);
            }
            __syncthreads();

            f32x4 S[8][2];
            #pragma unroll
            for (int jm = 0; jm < 8; jm++) {
                f16x8 kf[2];
                #pragma unroll
                for (int dblk = 0; dblk < 2; dblk++) {
                    int j = jm * 16 + l16;
                    int g = (dblk * 4 + quad) ^ (j & 7);
                    kf[dblk] = *(const f16x8*)(Ks + (size_t)(j * 8 + g) * 8);
                }
                #pragma unroll
                for (int qn = 0; qn < 2; qn++) {
                    f32x4 s = {};
                    s = __builtin_amdgcn_mfma_f32_16x16x32_f16(kf[0], qf[qn][0], s, 0, 0, 0);
                    s = __builtin_amdgcn_mfma_f32_16x16x32_f16(kf[1], qf[qn][1], s, 0, 0, 0);
                    S[jm][qn] = s;
                }
            }

            if (jt == qt) {
                #pragma unroll
                for (int jm = 0; jm < 8; jm++)
                    #pragma unroll
                    for (int qn = 0; qn < 2; qn++)
                        #pragma unroll
                        for (int r = 0; r < 4; r++) {
                            int jl = jm * 16 + quad * 4 + r;
                            int ql = w * 32 + qn * 16 + l16;
                            if (jl > ql) S[jm][qn][r] = -1e30f;
                        }
            }

            float alpha[2];
            #pragma unroll
            for (int qn = 0; qn < 2; qn++) {
                float tmax = -INFINITY;
                #pragma unroll
                for (int jm = 0; jm < 8; jm++)
                    #pragma unroll
                    for (int r = 0; r < 4; r++)
                        tmax = fmaxf(tmax, S[jm][qn][r]);
                tmax = fmaxf(tmax, __shfl_xor(tmax, 16));
                tmax = fmaxf(tmax, __shfl_xor(tmax, 32));
                float mnew = fmaxf(m_r[qn], tmax);
                alpha[qn] = __expf(m_r[qn] - mnew);
                m_r[qn] = mnew;
                float rsum = 0.0f;
                #pragma unroll
                for (int jm = 0; jm < 8; jm++)
                    #pragma unroll
                    for (int r = 0; r < 4; r++) {
                        float p = __expf(S[jm][qn][r] - mnew);
                        S[jm][qn][r] = p;
                        rsum += p;
                    }
                rsum += __shfl_xor(rsum, 16);
                rsum += __shfl_xor(rsum, 32);
                l_r[qn] = l_r[qn] * alpha[qn] + rsum;
            }

            #pragma unroll
            for (int jm = 0; jm < 8; jm++)
                #pragma unroll
                for (int qn = 0; qn < 2; qn++) {
                    f16x4 pk;
                    pk.x = (f16)S[jm][qn][0];
                    pk.y = (f16)S[jm][qn][1];
                    pk.z = (f16)S[jm][qn][2];
                    pk.w = (f16)S[jm][qn][3];
                    *(f16x4*)(Ps + (size_t)(qn * 16 + l16) * 136 + jm * 16 + quad * 4) = pk;
                }

            float aPV[2][4];
            #pragma unroll
            for (int m = 0; m < 2; m++)
                #pragma unroll
                for (int r = 0; r < 4; r++)
                    aPV[m][r] = __shfl(alpha[m], quad * 20 + r);
            #pragma unroll
            for (int m = 0; m < 2; m++)
                #pragma unroll
                for (int n = 0; n < 4; n++)
                    #pragma unroll
                    for (int r = 0; r < 4; r++)
                        Oacc[m][n][r] *= aPV[m][r];

            #pragma unroll
            for (int kblk = 0; kblk < 4; kblk++) {
                f16x8 pf[2];
                #pragma unroll
                for (int m = 0; m < 2; m++)
                    pf[m] = *(const f16x8*)(Ps + (size_t)(m * 16 + l16) * 136 +
                                            kblk * 32 + quad * 8);
                f16x8 vf[4];
                #pragma unroll
                for (int n = 0; n < 4; n++) {
                    int d = n * 16 + l16;
                    int g = (kblk * 4 + quad);
                    int gs = (g & 8) | ((g ^ d) & 7);
                    vf[n] = *(const f16x8*)(Vs + (size_t)(d * 16 + gs) * 8);
                }
                #pragma unroll
                for (int m = 0; m < 2; m++)
                    #pragma unroll
                    for (int n = 0; n < 4; n++)
                        Oacc[m][n] = __builtin_amdgcn_mfma_f32_16x16x32_f16(
                            pf[m], vf[n], Oacc[m][n], 0, 0, 0);
            }
        }

        #pragma unroll
        for (int m = 0; m < 2; m++) {
            float lPV[4];
            #pragma unroll
            for (int r = 0; r < 4; r++)
                lPV[r] = 1.0f / __shfl(l_r[m], quad * 20 + r);
            #pragma unroll
            for (int n = 0; n < 4; n++) {
                #pragma unroll
                for (int r = 0; r < 4; r++) {
                    int q = q0 + w * 32 + m * 16 + quad * 4 + r;
                    y[(size_t)(b * T_SEQ + q) * N_EMB + h * 64 + n * 16 + l16] =
                        (f16)(Oacc[m][n][r] * lPV[r]);
                }
            }
        }
    }
}

// ---------------------------------------------------------------- launch
extern "C" void kernel_launch(void* const* d_in, const int* in_sizes, int n_in,
                              void* d_out, int out_size, void* d_ws, size_t ws_size,
                              hipStream_t stream) {
    const float* x      = (const float*)d_in[0];
    const float* ln1_g  = (const float*)d_in[1];
    const float* ln1_b  = (const float*)d_in[2];
    const float* w_attn = (const float*)d_in[3];
    const float* b_attn = (const float*)d_in[4];
    const float* w_proj = (const float*)d_in[5];
    const float* b_proj = (const float*)d_in[6];
    const float* ln2_g  = (const float*)d_in[7];
    const float* ln2_b  = (const float*)d_in[8];
    const float* w_fc   = (const float*)d_in[9];
    const float* b_fc   = (const float*)d_in[10];
    const float* w_fc2  = (const float*)d_in[11];
    const float* b_fc2  = (const float*)d_in[12];
    float* out = (float*)d_out;

    const size_t MB = 1024 * 1024;
    char* ws = (char*)d_ws;
    f16*   lnbuf = (f16*)ws;                        // 16 MB
    f16*   qkbuf = (f16*)(ws + 16 * MB);            // 32 MB: [M][2048] Q|K
    f16*   vTbuf = (f16*)(ws + 48 * MB);            // 16 MB: [b][h][d][t]
    f16*   ybuf  = (f16*)(ws + 64 * MB);            // 16 MB
    f16*   h     = (f16*)(ws + 80 * MB);            // 64 MB
    f16*   wT    = (f16*)(ws + 144 * MB);           // 26 MB
    f16* wT_attn = wT;
    f16* wT_proj = wT_attn + (size_t)3072 * 1024;
    f16* wT_fc   = wT_proj + (size_t)1024 * 1024;
    f16* wT_fc2  = wT_fc   + (size_t)1024 * 4096;

    wconv_kernel<<<dim3(3072 / 32, 1024 / 32), 256, 0, stream>>>(w_attn, wT_attn, 1024, 3072);
    wconv_kernel<<<dim3(1024 / 32, 1024 / 32), 256, 0, stream>>>(w_proj, wT_proj, 1024, 1024);
    wconv_kernel<<<dim3(4096 / 32, 1024 / 32), 256, 0, stream>>>(w_fc,   wT_fc,   1024, 4096);
    wconv_kernel<<<dim3(1024 / 32, 4096 / 32), 256, 0, stream>>>(w_fc2,  wT_fc2,  4096, 1024);

    ln_kernel<<<M_ROWS, 256, 0, stream>>>(x, ln1_g, ln1_b, lnbuf);
    gemmX<3><<<dim3(3072 / 256, M_ROWS / 128), 512, 0, stream>>>(
        lnbuf, wT_attn, b_attn, nullptr, qkbuf, vTbuf, 1024, 3072);
    flash_kernel<<<dim3(8, 64), 256, 0, stream>>>(qkbuf, vTbuf, ybuf);
    gemm8<1, 128, 256><<<dim3(1024 / 256, M_ROWS / 128), 512, 0, stream>>>(
        ybuf, wT_proj, b_proj, x, out, 1024, 1024);
    ln_kernel<<<M_ROWS, 256, 0, stream>>>(out, ln2_g, ln2_b, lnbuf);
    gemmX<2><<<dim3(4096 / 256, M_ROWS / 128), 512, 0, stream>>>(
        lnbuf, wT_fc, b_fc, nullptr, h, nullptr, 1024, 4096);
    gemm8<1, 128, 256><<<dim3(1024 / 256, M_ROWS / 128), 512, 0, stream>>>(
        h, wT_fc2, b_fc2, out, out, 4096, 1024);
}